// Round 6
// baseline (334.001 us; speedup 1.0000x reference)
//
#include <hip/hip_runtime.h>
#include <hip/hip_bf16.h>

#define N_NODES 50000
#define NP1     50001
#define N_EDGES 800000
#define NFEAT   256
#define NHID    64
#define HEADS   4
#define NCLASS  16
#define NEG_SLOPE 0.2f

#define NB_HIST 782  // (N_EDGES/4 + 255)/256

typedef __attribute__((ext_vector_type(8))) short short8;
typedef __attribute__((ext_vector_type(4))) float floatx4;

__device__ __forceinline__ float blo(unsigned int u) { return __uint_as_float(u << 16); }
__device__ __forceinline__ float bhi(unsigned int u) { return __uint_as_float(u & 0xffff0000u); }
__device__ __forceinline__ unsigned short f2b(float f) {
    unsigned int x = __float_as_uint(f);
    unsigned int r = x + 0x7fffu + ((x >> 16) & 1u);
    return (unsigned short)(r >> 16);
}
__device__ __forceinline__ unsigned int pack2(float a, float b) {
    return (unsigned int)f2b(a) | ((unsigned int)f2b(b) << 16);
}
__device__ __forceinline__ float leaky(float x) { return fmaxf(x, NEG_SLOPE * x); }

// ---------------- fused hist + weight prep ----------------
// blocks [0, NB_HIST): edge histogram (4 edges/thread)
// blocks [NB_HIST, NB_HIST+16): coalesced LDS-tile transpose W1 -> W1E (bf16)
// blocks [NB_HIST+16, NB_HIST+20): Wel/Wer fold, one block per head (wave-reduce)
// block NB_HIST+20: W2T transpose + zero-pad rows 264..271
__global__ __launch_bounds__(256) void hist_prep_kernel(
        const int* __restrict__ dst, int* __restrict__ cnt,
        const float* __restrict__ W1, const float* __restrict__ W2,
        const float* __restrict__ al1, const float* __restrict__ ar1,
        unsigned short* __restrict__ W1E, unsigned short* __restrict__ W2T) {
    int b = blockIdx.x, t = threadIdx.x;
    if (b < NB_HIST) {
        int e = (b * 256 + t) * 4;
        if (e < N_EDGES) {
            int4 d = *(const int4*)&dst[e];
            atomicAdd(&cnt[d.x], 1);
            atomicAdd(&cnt[d.y], 1);
            atomicAdd(&cnt[d.z], 1);
            atomicAdd(&cnt[d.w], 1);
        }
        return;
    }
    int pb = b - NB_HIST;
    if (pb < 16) {
        // transpose 64x64 tile: tk = row range of W1 (k), tn = col range (n)
        __shared__ float tile[64][65];
        int tk = (pb & 3) * 64, tn = (pb >> 2) * 64;
        int tx = t & 63, ty = t >> 6;
#pragma unroll
        for (int r = 0; r < 16; ++r) {
            int row = ty * 16 + r;
            tile[row][tx] = W1[(tk + row) * 256 + tn + tx];
        }
        __syncthreads();
#pragma unroll
        for (int r = 0; r < 16; ++r) {
            int row = ty * 16 + r;
            W1E[(tn + row) * 256 + tk + tx] = f2b(tile[tx][row]);
        }
    } else if (pb < 20) {
        // Wel/Wer for head h: wave w handles k = w,w+4,...
        int h = pb - 16;
        int w = t >> 6, lane = t & 63;
        float alv = al1[h * 64 + lane];
        float arv = ar1[h * 64 + lane];
        for (int k = w; k < 256; k += 4) {
            float wv = W1[k * 256 + h * 64 + lane];
            float sl = wv * alv, sr = wv * arv;
#pragma unroll
            for (int off = 1; off < 64; off <<= 1) {
                sl += __shfl_xor(sl, off);
                sr += __shfl_xor(sr, off);
            }
            if (lane == 0) {
                W1E[(256 + h) * 256 + k] = f2b(sl);
                W1E[(260 + h) * 256 + k] = f2b(sr);
            }
        }
    } else {
        // W2T [16 n][256 k] + zero pad rows 264..271
        int n = t >> 4, k0 = (t & 15) * 16;
#pragma unroll
        for (int j = 0; j < 16; ++j)
            W2T[n * 256 + k0 + j] = f2b(W2[(k0 + j) * 16 + n]);
#pragma unroll
        for (int j = 0; j < 8; ++j)
            W1E[264 * 256 + j * 256 + t] = 0;
    }
}

// ---------------- CSR scan ----------------
__global__ __launch_bounds__(256) void scan1_kernel(const int* __restrict__ cnt,
                                                    int* __restrict__ partial,
                                                    int* __restrict__ bsum) {
    __shared__ int wsum[4];
    int t = threadIdx.x;
    int base = blockIdx.x * 1024 + t * 4;
    int v0 = (base + 0 < N_NODES) ? cnt[base + 0] : 0;
    int v1 = (base + 1 < N_NODES) ? cnt[base + 1] : 0;
    int v2 = (base + 2 < N_NODES) ? cnt[base + 2] : 0;
    int v3 = (base + 3 < N_NODES) ? cnt[base + 3] : 0;
    int s = v0 + v1 + v2 + v3;
    int lane = t & 63, w = t >> 6;
    int incl = s;
#pragma unroll
    for (int off = 1; off < 64; off <<= 1) {
        int x = __shfl_up(incl, off);
        if (lane >= off) incl += x;
    }
    if (lane == 63) wsum[w] = incl;
    __syncthreads();
    int woff = 0;
    for (int k = 0; k < w; ++k) woff += wsum[k];
    int excl = woff + incl - s;
    if (base + 0 < NP1) partial[base + 0] = excl;
    if (base + 1 < NP1) partial[base + 1] = excl + v0;
    if (base + 2 < NP1) partial[base + 2] = excl + v0 + v1;
    if (base + 3 < NP1) partial[base + 3] = excl + v0 + v1 + v2;
    if (t == 255) bsum[blockIdx.x] = woff + incl;
}

__global__ void scan3_kernel(const int* __restrict__ partial, const int* __restrict__ bsum,
                             int* __restrict__ row_ptr, int* __restrict__ fill) {
    __shared__ int sb[64];
    int t = threadIdx.x;
    if (t < 64) {
        int v = (t < 49) ? bsum[t] : 0;
        int incl = v;
#pragma unroll
        for (int off = 1; off < 64; off <<= 1) {
            int x = __shfl_up(incl, off);
            if (t >= off) incl += x;
        }
        sb[t] = incl - v;
    }
    __syncthreads();
    int i = blockIdx.x * 256 + t;
    if (i < NP1) {
        int v = partial[i] + sb[i >> 10];
        row_ptr[i] = v;
        if (i < N_NODES) fill[i] = v;
    }
}

__global__ void scatter_kernel(const int* __restrict__ src, const int* __restrict__ dst,
                               int* __restrict__ fill, int* __restrict__ csr_src) {
    int e = (blockIdx.x * blockDim.x + threadIdx.x) * 4;
    if (e < N_EDGES) {
        int4 d = *(const int4*)&dst[e];
        int4 s = *(const int4*)&src[e];
        csr_src[atomicAdd(&fill[d.x], 1)] = s.x;
        csr_src[atomicAdd(&fill[d.y], 1)] = s.y;
        csr_src[atomicAdd(&fill[d.z], 1)] = s.z;
        csr_src[atomicAdd(&fill[d.w], 1)] = s.w;
    }
}

// ---------------- GEMM1 (bf16 MFMA): [feat1 | el | er] = x @ [W1 | Wel | Wer] ----------------
__global__ __launch_bounds__(256, 2) void gemm1_mfma_kernel(
        const float* __restrict__ X, const unsigned short* __restrict__ BT,
        unsigned short* __restrict__ C, float* __restrict__ el, float* __restrict__ er) {
    __shared__ __align__(16) unsigned short As[128 * 40];
    __shared__ __align__(16) unsigned short Bs[272 * 40];
    int t = threadIdx.x;
    int m0 = blockIdx.x * 128;
    int lane = t & 63, wm = t >> 6;
    int quad = lane >> 4, l16 = lane & 15;

    floatx4 acc[2][17];
#pragma unroll
    for (int i = 0; i < 2; ++i)
#pragma unroll
        for (int j = 0; j < 17; ++j) acc[i][j] = (floatx4){0.f, 0.f, 0.f, 0.f};

    int arow = t >> 1, ak = (t & 1) * 16;
    int grow = m0 + arow;
    const float* xrow = X + (size_t)grow * 256 + ak;

    for (int k0 = 0; k0 < 256; k0 += 32) {
        float4 v0 = make_float4(0.f, 0.f, 0.f, 0.f), v1 = v0, v2 = v0, v3 = v0;
        if (grow < N_NODES) {
            v0 = *(const float4*)(xrow + k0 + 0);
            v1 = *(const float4*)(xrow + k0 + 4);
            v2 = *(const float4*)(xrow + k0 + 8);
            v3 = *(const float4*)(xrow + k0 + 12);
        }
        uint4 p0, p1;
        p0.x = pack2(v0.x, v0.y); p0.y = pack2(v0.z, v0.w);
        p0.z = pack2(v1.x, v1.y); p0.w = pack2(v1.z, v1.w);
        p1.x = pack2(v2.x, v2.y); p1.y = pack2(v2.z, v2.w);
        p1.z = pack2(v3.x, v3.y); p1.w = pack2(v3.z, v3.w);
        *(uint4*)&As[arow * 40 + ak] = p0;
        *(uint4*)&As[arow * 40 + ak + 8] = p1;
#pragma unroll
        for (int i = 0; i < 5; ++i) {
            int ch = t + i * 256;
            if (ch < 1088) {
                int row = ch >> 2, off = (ch & 3) * 8;
                *(uint4*)&Bs[row * 40 + off] = *(const uint4*)(BT + row * 256 + k0 + off);
            }
        }
        __syncthreads();

        short8 a0 = *(const short8*)&As[(wm * 32 + l16) * 40 + quad * 8];
        short8 a1 = *(const short8*)&As[(wm * 32 + 16 + l16) * 40 + quad * 8];
#pragma unroll
        for (int nf = 0; nf < 17; ++nf) {
            short8 bb = *(const short8*)&Bs[(nf * 16 + l16) * 40 + quad * 8];
            acc[0][nf] = __builtin_amdgcn_mfma_f32_16x16x32_bf16(a0, bb, acc[0][nf], 0, 0, 0);
            acc[1][nf] = __builtin_amdgcn_mfma_f32_16x16x32_bf16(a1, bb, acc[1][nf], 0, 0, 0);
        }
        __syncthreads();
    }

#pragma unroll
    for (int mf = 0; mf < 2; ++mf) {
#pragma unroll
        for (int r = 0; r < 4; ++r) {
            int row = m0 + wm * 32 + mf * 16 + quad * 4 + r;
            if (row < N_NODES && l16 < 8) {
                float v = acc[mf][16][r];
                if (l16 < 4) el[row * 4 + l16] = v;
                else er[row * 4 + (l16 - 4)] = v;
            }
        }
    }

    unsigned short* scr = Bs + wm * 1536;
    int half = lane >> 5, l32 = lane & 31;
    int rrow = l32 >> 1, coff = (l32 & 1) * 8;
#pragma unroll
    for (int mf = 0; mf < 2; ++mf) {
#pragma unroll
        for (int p = 0; p < 8; ++p) {
            unsigned short* base = scr + (p & 1) * 768;
#pragma unroll
            for (int fr = 0; fr < 2; ++fr) {
                int nf = 2 * p + fr;
                unsigned short* fb = base + fr * 384;
#pragma unroll
                for (int r = 0; r < 4; ++r)
                    fb[(quad * 4 + r) * 24 + l16] = f2b(acc[mf][nf][r]);
            }
            uint4 val = *(const uint4*)(base + half * 384 + rrow * 24 + coff);
            int row = m0 + wm * 32 + mf * 16 + rrow;
            int nf = 2 * p + half;
            if (row < N_NODES)
                *(uint4*)&C[(size_t)row * 256 + nf * 16 + coff] = val;
        }
    }
}

// ---------------- layer-1 aggregation: quarter-wave per edge, 2x unroll ----------------
__global__ void agg1_kernel(const unsigned short* __restrict__ feat1,
                            const float* __restrict__ el, const float* __restrict__ er,
                            const int* __restrict__ row_ptr, const int* __restrict__ csr_src,
                            const float* __restrict__ b1, unsigned short* __restrict__ h1b) {
    int wave = threadIdx.x >> 6, lane = threadIdx.x & 63;
    int n = blockIdx.x * 4 + wave;
    if (n >= N_NODES) return;
    int q = lane >> 4, l16 = lane & 15;
    int h = l16 >> 2;
    float er_h = er[n * 4 + h];
    int start = row_ptr[n], end = row_ptr[n + 1];

    float acc[16];
#pragma unroll
    for (int j = 0; j < 16; ++j) acc[j] = 0.f;
    float denom = 0.f;

    int i = start + q;
    for (; i + 4 < end; i += 8) {
        int s0 = csr_src[i];
        int s1 = csr_src[i + 4];
        float ex0 = __expf(leaky(el[s0 * 4 + h] + er_h));
        float ex1 = __expf(leaky(el[s1 * 4 + h] + er_h));
        const uint4* p0 = (const uint4*)(feat1 + (size_t)s0 * 256 + l16 * 16);
        const uint4* p1 = (const uint4*)(feat1 + (size_t)s1 * 256 + l16 * 16);
        uint4 a0 = p0[0], a1 = p0[1];
        uint4 b0 = p1[0], b1v = p1[1];
        denom += ex0 + ex1;
        acc[0]  = fmaf(blo(a0.x), ex0, acc[0]);   acc[0]  = fmaf(blo(b0.x), ex1, acc[0]);
        acc[1]  = fmaf(bhi(a0.x), ex0, acc[1]);   acc[1]  = fmaf(bhi(b0.x), ex1, acc[1]);
        acc[2]  = fmaf(blo(a0.y), ex0, acc[2]);   acc[2]  = fmaf(blo(b0.y), ex1, acc[2]);
        acc[3]  = fmaf(bhi(a0.y), ex0, acc[3]);   acc[3]  = fmaf(bhi(b0.y), ex1, acc[3]);
        acc[4]  = fmaf(blo(a0.z), ex0, acc[4]);   acc[4]  = fmaf(blo(b0.z), ex1, acc[4]);
        acc[5]  = fmaf(bhi(a0.z), ex0, acc[5]);   acc[5]  = fmaf(bhi(b0.z), ex1, acc[5]);
        acc[6]  = fmaf(blo(a0.w), ex0, acc[6]);   acc[6]  = fmaf(blo(b0.w), ex1, acc[6]);
        acc[7]  = fmaf(bhi(a0.w), ex0, acc[7]);   acc[7]  = fmaf(bhi(b0.w), ex1, acc[7]);
        acc[8]  = fmaf(blo(a1.x), ex0, acc[8]);   acc[8]  = fmaf(blo(b1v.x), ex1, acc[8]);
        acc[9]  = fmaf(bhi(a1.x), ex0, acc[9]);   acc[9]  = fmaf(bhi(b1v.x), ex1, acc[9]);
        acc[10] = fmaf(blo(a1.y), ex0, acc[10]);  acc[10] = fmaf(blo(b1v.y), ex1, acc[10]);
        acc[11] = fmaf(bhi(a1.y), ex0, acc[11]);  acc[11] = fmaf(bhi(b1v.y), ex1, acc[11]);
        acc[12] = fmaf(blo(a1.z), ex0, acc[12]);  acc[12] = fmaf(blo(b1v.z), ex1, acc[12]);
        acc[13] = fmaf(bhi(a1.z), ex0, acc[13]);  acc[13] = fmaf(bhi(b1v.z), ex1, acc[13]);
        acc[14] = fmaf(blo(a1.w), ex0, acc[14]);  acc[14] = fmaf(blo(b1v.w), ex1, acc[14]);
        acc[15] = fmaf(bhi(a1.w), ex0, acc[15]);  acc[15] = fmaf(bhi(b1v.w), ex1, acc[15]);
    }
    if (i < end) {
        int s = csr_src[i];
        float ex = __expf(leaky(el[s * 4 + h] + er_h));
        const uint4* p = (const uint4*)(feat1 + (size_t)s * 256 + l16 * 16);
        uint4 u0 = p[0], u1 = p[1];
        denom += ex;
        acc[0]  = fmaf(blo(u0.x), ex, acc[0]);
        acc[1]  = fmaf(bhi(u0.x), ex, acc[1]);
        acc[2]  = fmaf(blo(u0.y), ex, acc[2]);
        acc[3]  = fmaf(bhi(u0.y), ex, acc[3]);
        acc[4]  = fmaf(blo(u0.z), ex, acc[4]);
        acc[5]  = fmaf(bhi(u0.z), ex, acc[5]);
        acc[6]  = fmaf(blo(u0.w), ex, acc[6]);
        acc[7]  = fmaf(bhi(u0.w), ex, acc[7]);
        acc[8]  = fmaf(blo(u1.x), ex, acc[8]);
        acc[9]  = fmaf(bhi(u1.x), ex, acc[9]);
        acc[10] = fmaf(blo(u1.y), ex, acc[10]);
        acc[11] = fmaf(bhi(u1.y), ex, acc[11]);
        acc[12] = fmaf(blo(u1.z), ex, acc[12]);
        acc[13] = fmaf(bhi(u1.z), ex, acc[13]);
        acc[14] = fmaf(blo(u1.w), ex, acc[14]);
        acc[15] = fmaf(bhi(u1.w), ex, acc[15]);
    }
#pragma unroll
    for (int j = 0; j < 16; ++j) {
        acc[j] += __shfl_xor(acc[j], 16);
        acc[j] += __shfl_xor(acc[j], 32);
    }
    denom += __shfl_xor(denom, 16);
    denom += __shfl_xor(denom, 32);

    if (q == 0) {
        float inv = (end > start) ? 1.f / denom : 0.f;
        float o[16];
#pragma unroll
        for (int j = 0; j < 16; j += 4) {
            float4 b4 = *(const float4*)&b1[l16 * 16 + j];
            o[j + 0] = fmaf(acc[j + 0], inv, b4.x);
            o[j + 1] = fmaf(acc[j + 1], inv, b4.y);
            o[j + 2] = fmaf(acc[j + 2], inv, b4.z);
            o[j + 3] = fmaf(acc[j + 3], inv, b4.w);
        }
#pragma unroll
        for (int j = 0; j < 16; ++j) o[j] = o[j] > 0.f ? o[j] : __expf(o[j]) - 1.f;
        uint4 pa, pb;
        pa.x = pack2(o[0], o[1]);   pa.y = pack2(o[2], o[3]);
        pa.z = pack2(o[4], o[5]);   pa.w = pack2(o[6], o[7]);
        pb.x = pack2(o[8], o[9]);   pb.y = pack2(o[10], o[11]);
        pb.z = pack2(o[12], o[13]); pb.w = pack2(o[14], o[15]);
        uint4* dstp = (uint4*)(h1b + (size_t)n * 256 + l16 * 16);
        dstp[0] = pa;
        dstp[1] = pb;
    }
}

// ---------------- GEMM2 (bf16 MFMA, no LDS) + fused el2/er2 ----------------
__global__ __launch_bounds__(256) void gemm2_mfma_kernel(
        const unsigned short* __restrict__ h1b, const unsigned short* __restrict__ W2T,
        const float* __restrict__ al2, const float* __restrict__ ar2,
        float* __restrict__ feat2, float* __restrict__ el2, float* __restrict__ er2) {
    int wave = threadIdx.x >> 6, lane = threadIdx.x & 63;
    int l16 = lane & 15, quad = lane >> 4;
    int row0 = (blockIdx.x * 4 + wave) * 16;
    if (row0 >= N_NODES) return;
    floatx4 acc = (floatx4){0.f, 0.f, 0.f, 0.f};
    const unsigned short* arow = h1b + (size_t)(row0 + l16) * 256 + quad * 8;
    const unsigned short* brow = W2T + (size_t)l16 * 256 + quad * 8;
#pragma unroll
    for (int k0 = 0; k0 < 256; k0 += 32) {
        short8 a = *(const short8*)(arow + k0);
        short8 b = *(const short8*)(brow + k0);
        acc = __builtin_amdgcn_mfma_f32_16x16x32_bf16(a, b, acc, 0, 0, 0);
    }
    float a2 = al2[l16], r2 = ar2[l16];
#pragma unroll
    for (int r = 0; r < 4; ++r) {
        int row = row0 + quad * 4 + r;
        float v = acc[r];
        feat2[row * 16 + l16] = v;
        float pl = v * a2, pr = v * r2;
#pragma unroll
        for (int off = 1; off < 16; off <<= 1) {
            pl += __shfl_xor(pl, off);
            pr += __shfl_xor(pr, off);
        }
        if (l16 == 0) {
            el2[row] = pl;
            er2[row] = pr;
        }
    }
}

// ---------------- layer-2 aggregation + log_softmax, 2x unroll ----------------
__global__ void agg2_kernel(const float* __restrict__ feat2, const float* __restrict__ el2,
                            const float* __restrict__ er2, const int* __restrict__ row_ptr,
                            const int* __restrict__ csr_src, const float* __restrict__ b2,
                            float* __restrict__ out) {
    int wave = threadIdx.x >> 6, lane = threadIdx.x & 63;
    int n = blockIdx.x * 4 + wave;
    if (n >= N_NODES) return;
    int start = row_ptr[n], end = row_ptr[n + 1];
    float ern = er2[n];
    int eo = lane >> 4, c = lane & 15;
    float acc = 0.f, denom = 0.f;
    int i = start + eo;
    for (; i + 4 < end; i += 8) {
        int s0 = csr_src[i], s1 = csr_src[i + 4];
        float ex0 = __expf(leaky(el2[s0] + ern));
        float ex1 = __expf(leaky(el2[s1] + ern));
        float f0 = feat2[s0 * 16 + c], f1 = feat2[s1 * 16 + c];
        denom += ex0 + ex1;
        acc = fmaf(f0, ex0, acc);
        acc = fmaf(f1, ex1, acc);
    }
    if (i < end) {
        int s = csr_src[i];
        float ex = __expf(leaky(el2[s] + ern));
        denom += ex;
        acc = fmaf(feat2[s * 16 + c], ex, acc);
    }
    acc += __shfl_xor(acc, 16);
    acc += __shfl_xor(acc, 32);
    denom += __shfl_xor(denom, 16);
    denom += __shfl_xor(denom, 32);
    float v = ((end > start) ? acc / denom : 0.f) + b2[c];
    float mx = v;
#pragma unroll
    for (int off = 1; off < 16; off <<= 1) mx = fmaxf(mx, __shfl_xor(mx, off));
    float ex2 = __expf(v - mx);
    float s2 = ex2;
#pragma unroll
    for (int off = 1; off < 16; off <<= 1) s2 += __shfl_xor(s2, off);
    float res = v - mx - logf(s2);
    if (lane < 16) out[n * 16 + lane] = res;
}

// ---------------- launch ----------------
extern "C" void kernel_launch(void* const* d_in, const int* in_sizes, int n_in,
                              void* d_out, int out_size, void* d_ws, size_t ws_size,
                              hipStream_t stream) {
    const float* x   = (const float*)d_in[0];
    const int*   src = (const int*)d_in[1];
    const int*   dst = (const int*)d_in[2];
    const float* W1  = (const float*)d_in[3];
    const float* al1 = (const float*)d_in[4];
    const float* ar1 = (const float*)d_in[5];
    const float* b1  = (const float*)d_in[6];
    const float* W2  = (const float*)d_in[7];
    const float* al2 = (const float*)d_in[8];
    const float* ar2 = (const float*)d_in[9];
    const float* b2  = (const float*)d_in[10];
    float* out = (float*)d_out;

    char* ws = (char*)d_ws;
    size_t off = 0;
    auto alloc = [&](size_t bytes) -> void* {
        void* p = ws + off;
        off += (bytes + 255) & ~(size_t)255;
        return p;
    };
    unsigned short* W1E   = (unsigned short*)alloc((size_t)272 * 256 * 2);
    unsigned short* W2T   = (unsigned short*)alloc((size_t)16 * 256 * 2);
    unsigned short* feat1 = (unsigned short*)alloc((size_t)N_NODES * 256 * 2);
    unsigned short* h1b   = (unsigned short*)alloc((size_t)N_NODES * 256 * 2);
    float* feat2   = (float*)alloc((size_t)N_NODES * 16 * 4);
    float* el1     = (float*)alloc((size_t)N_NODES * 4 * 4);
    float* er1     = (float*)alloc((size_t)N_NODES * 4 * 4);
    float* el2     = (float*)alloc((size_t)N_NODES * 4);
    float* er2     = (float*)alloc((size_t)N_NODES * 4);
    int*   cnt     = (int*)alloc((size_t)N_NODES * 4);
    int*   fill    = (int*)alloc((size_t)N_NODES * 4);
    int*   row_ptr = (int*)alloc((size_t)NP1 * 4);
    int*   partial = (int*)alloc((size_t)NP1 * 4);
    int*   bsum    = (int*)alloc((size_t)64 * 4);
    int*   csr_src = (int*)alloc((size_t)N_EDGES * 4);

    hipMemsetAsync(cnt, 0, (size_t)N_NODES * 4, stream);

    dim3 b256(256);
    hist_prep_kernel<<<NB_HIST + 21, b256, 0, stream>>>(dst, cnt, W1, W2, al1, ar1, W1E, W2T);
    scan1_kernel<<<49, b256, 0, stream>>>(cnt, partial, bsum);
    scan3_kernel<<<(NP1 + 255) / 256, b256, 0, stream>>>(partial, bsum, row_ptr, fill);
    scatter_kernel<<<(N_EDGES / 4 + 255) / 256, b256, 0, stream>>>(src, dst, fill, csr_src);

    gemm1_mfma_kernel<<<(N_NODES + 127) / 128, b256, 0, stream>>>(x, W1E, feat1, el1, er1);
    agg1_kernel<<<(N_NODES + 3) / 4, b256, 0, stream>>>(feat1, el1, er1, row_ptr, csr_src, b1, h1b);

    gemm2_mfma_kernel<<<(N_NODES + 63) / 64, b256, 0, stream>>>(h1b, W2T, al2, ar2, feat2, el2, er2);
    agg2_kernel<<<(N_NODES + 3) / 4, b256, 0, stream>>>(feat2, el2, er2, row_ptr, csr_src, b2, out);
}

// Round 7
// 276.870 us; speedup vs baseline: 1.2063x; 1.2063x over previous
//
#include <hip/hip_runtime.h>
#include <hip/hip_bf16.h>

#define N_NODES 50000
#define NP1     50001
#define N_EDGES 800000
#define NFEAT   256
#define NHID    64
#define HEADS   4
#define NCLASS  16
#define NEG_SLOPE 0.2f

#define NBLK  782                 // edge blocks (1024 edges each)
#define NBUCK 196                 // buckets of 256 nodes (dst >> 8)
#define NSCAN (NBUCK * NBLK)      // 153272
#define NSCB  150                 // ceil(NSCAN / 1024)

typedef __attribute__((ext_vector_type(8))) short short8;
typedef __attribute__((ext_vector_type(4))) float floatx4;

__device__ __forceinline__ float blo(unsigned int u) { return __uint_as_float(u << 16); }
__device__ __forceinline__ float bhi(unsigned int u) { return __uint_as_float(u & 0xffff0000u); }
__device__ __forceinline__ unsigned short f2b(float f) {
    unsigned int x = __float_as_uint(f);
    unsigned int r = x + 0x7fffu + ((x >> 16) & 1u);
    return (unsigned short)(r >> 16);
}
__device__ __forceinline__ unsigned int pack2(float a, float b) {
    return (unsigned int)f2b(a) | ((unsigned int)f2b(b) << 16);
}
__device__ __forceinline__ float leaky(float x) { return fmaxf(x, NEG_SLOPE * x); }

// ---------------- P1: per-block bucket histogram + fused weight prep ----------------
// blocks [0, NBLK): LDS bucket hist of 1024 edges -> bhist[bucket][block]
// blocks [NBLK, NBLK+16): W1 transpose tiles; [NBLK+16, NBLK+20): Wel/Wer; NBLK+20: W2T
__global__ __launch_bounds__(256) void p1_kernel(
        const int* __restrict__ dst, int* __restrict__ bhist,
        const float* __restrict__ W1, const float* __restrict__ W2,
        const float* __restrict__ al1, const float* __restrict__ ar1,
        unsigned short* __restrict__ W1E, unsigned short* __restrict__ W2T) {
    __shared__ float tile[64][65];
    __shared__ int hist[NBUCK];
    int b = blockIdx.x, t = threadIdx.x;
    if (b < NBLK) {
        if (t < NBUCK) hist[t] = 0;
        __syncthreads();
        int e = (b * 256 + t) * 4;
        if (e < N_EDGES) {
            int4 d = *(const int4*)&dst[e];
            atomicAdd(&hist[d.x >> 8], 1);
            atomicAdd(&hist[d.y >> 8], 1);
            atomicAdd(&hist[d.z >> 8], 1);
            atomicAdd(&hist[d.w >> 8], 1);
        }
        __syncthreads();
        if (t < NBUCK) bhist[t * NBLK + b] = hist[t];
        return;
    }
    int pb = b - NBLK;
    if (pb < 16) {
        int tk = (pb & 3) * 64, tn = (pb >> 2) * 64;
        int tx = t & 63, ty = t >> 6;
#pragma unroll
        for (int r = 0; r < 16; ++r) {
            int row = ty * 16 + r;
            tile[row][tx] = W1[(tk + row) * 256 + tn + tx];
        }
        __syncthreads();
#pragma unroll
        for (int r = 0; r < 16; ++r) {
            int row = ty * 16 + r;
            W1E[(tn + row) * 256 + tk + tx] = f2b(tile[tx][row]);
        }
    } else if (pb < 20) {
        int h = pb - 16;
        int w = t >> 6, lane = t & 63;
        float alv = al1[h * 64 + lane];
        float arv = ar1[h * 64 + lane];
        for (int k = w; k < 256; k += 4) {
            float wv = W1[k * 256 + h * 64 + lane];
            float sl = wv * alv, sr = wv * arv;
#pragma unroll
            for (int off = 1; off < 64; off <<= 1) {
                sl += __shfl_xor(sl, off);
                sr += __shfl_xor(sr, off);
            }
            if (lane == 0) {
                W1E[(256 + h) * 256 + k] = f2b(sl);
                W1E[(260 + h) * 256 + k] = f2b(sr);
            }
        }
    } else {
        int n = t >> 4, k0 = (t & 15) * 16;
#pragma unroll
        for (int j = 0; j < 16; ++j)
            W2T[n * 256 + k0 + j] = f2b(W2[(k0 + j) * 16 + n]);
#pragma unroll
        for (int j = 0; j < 8; ++j)
            W1E[264 * 256 + j * 256 + t] = 0;
    }
}

// ---------------- scanA: per-chunk (1024) exclusive scan of bhist ----------------
__global__ __launch_bounds__(256) void scanA_kernel(const int* __restrict__ bhist,
                                                    int* __restrict__ partial,
                                                    int* __restrict__ bsum) {
    __shared__ int wsum[4];
    int t = threadIdx.x;
    int base = blockIdx.x * 1024 + t * 4;
    int v0 = (base + 0 < NSCAN) ? bhist[base + 0] : 0;
    int v1 = (base + 1 < NSCAN) ? bhist[base + 1] : 0;
    int v2 = (base + 2 < NSCAN) ? bhist[base + 2] : 0;
    int v3 = (base + 3 < NSCAN) ? bhist[base + 3] : 0;
    int s = v0 + v1 + v2 + v3;
    int lane = t & 63, w = t >> 6;
    int incl = s;
#pragma unroll
    for (int off = 1; off < 64; off <<= 1) {
        int x = __shfl_up(incl, off);
        if (lane >= off) incl += x;
    }
    if (lane == 63) wsum[w] = incl;
    __syncthreads();
    int woff = 0;
    for (int k = 0; k < w; ++k) woff += wsum[k];
    int excl = woff + incl - s;
    if (base + 0 < NSCAN) partial[base + 0] = excl;
    if (base + 1 < NSCAN) partial[base + 1] = excl + v0;
    if (base + 2 < NSCAN) partial[base + 2] = excl + v0 + v1;
    if (base + 3 < NSCAN) partial[base + 3] = excl + v0 + v1 + v2;
    if (t == 255) bsum[blockIdx.x] = woff + incl;
}

// ---------------- scanB: scan the 150 chunk sums + apply ----------------
__global__ __launch_bounds__(256) void scanB_kernel(const int* __restrict__ partial,
                                                    const int* __restrict__ bsum,
                                                    int* __restrict__ scanned) {
    __shared__ int wsum[4];
    __shared__ int sb[256];
    int t = threadIdx.x;
    int v = (t < NSCB) ? bsum[t] : 0;
    int lane = t & 63, w = t >> 6;
    int incl = v;
#pragma unroll
    for (int off = 1; off < 64; off <<= 1) {
        int x = __shfl_up(incl, off);
        if (lane >= off) incl += x;
    }
    if (lane == 63) wsum[w] = incl;
    __syncthreads();
    int woff = 0;
    for (int k = 0; k < w; ++k) woff += wsum[k];
    sb[t] = woff + incl - v;
    __syncthreads();
    int base = blockIdx.x * 1024 + t * 4;
#pragma unroll
    for (int j = 0; j < 4; ++j) {
        int i = base + j;
        if (i < NSCAN) scanned[i] = partial[i] + sb[i >> 10];
    }
}

// ---------------- P2: scatter edges into bucket-sorted ebuf (LDS slot atomics) ----------------
__global__ __launch_bounds__(256) void p2_kernel(const int* __restrict__ src,
                                                 const int* __restrict__ dst,
                                                 const int* __restrict__ scanned,
                                                 int* __restrict__ ebuf) {
    __shared__ int bs[NBUCK];
    int b = blockIdx.x, t = threadIdx.x;
    if (t < NBUCK) bs[t] = scanned[t * NBLK + b];
    __syncthreads();
    int e = (b * 256 + t) * 4;
    if (e < N_EDGES) {
        int4 d = *(const int4*)&dst[e];
        int4 s = *(const int4*)&src[e];
        int p0 = atomicAdd(&bs[d.x >> 8], 1);
        ebuf[p0] = (s.x << 8) | (d.x & 255);
        int p1 = atomicAdd(&bs[d.y >> 8], 1);
        ebuf[p1] = (s.y << 8) | (d.y & 255);
        int p2 = atomicAdd(&bs[d.z >> 8], 1);
        ebuf[p2] = (s.z << 8) | (d.z & 255);
        int p3 = atomicAdd(&bs[d.w >> 8], 1);
        ebuf[p3] = (s.w << 8) | (d.w & 255);
    }
}

// ---------------- P3: per-bucket CSR finalize (row_ptr + csr_src) ----------------
__global__ __launch_bounds__(256) void p3_kernel(const int* __restrict__ scanned,
                                                 const int* __restrict__ ebuf,
                                                 int* __restrict__ row_ptr,
                                                 int* __restrict__ csr_src) {
    __shared__ int lcnt[256];
    __shared__ int loff[256];
    __shared__ int wsum[4];
    int b = blockIdx.x, t = threadIdx.x;
    int base = scanned[b * NBLK];
    int endb = (b == NBUCK - 1) ? N_EDGES : scanned[(b + 1) * NBLK];
    lcnt[t] = 0;
    __syncthreads();
    for (int i = base + t; i < endb; i += 256)
        atomicAdd(&lcnt[ebuf[i] & 255], 1);
    __syncthreads();
    int v = lcnt[t];
    int lane = t & 63, w = t >> 6;
    int incl = v;
#pragma unroll
    for (int off = 1; off < 64; off <<= 1) {
        int x = __shfl_up(incl, off);
        if (lane >= off) incl += x;
    }
    if (lane == 63) wsum[w] = incl;
    __syncthreads();
    int woff = 0;
    for (int k = 0; k < w; ++k) woff += wsum[k];
    int excl = woff + incl - v;
    loff[t] = base + excl;
    int node = b * 256 + t;
    if (node < NP1) row_ptr[node] = base + excl;
    if (b == NBUCK - 1 && t == 255) row_ptr[N_NODES] = N_EDGES;  // safety (node 50000 covered at t=80 too)
    __syncthreads();
    for (int i = base + t; i < endb; i += 256) {
        int p = ebuf[i];
        int pos = atomicAdd(&loff[p & 255], 1);
        csr_src[pos] = p >> 8;
    }
}

// ---------------- GEMM1 (bf16 MFMA): [feat1 | el | er] = x @ [W1 | Wel | Wer] ----------------
__global__ __launch_bounds__(256, 2) void gemm1_mfma_kernel(
        const float* __restrict__ X, const unsigned short* __restrict__ BT,
        unsigned short* __restrict__ C, float* __restrict__ el, float* __restrict__ er) {
    __shared__ __align__(16) unsigned short As[128 * 40];
    __shared__ __align__(16) unsigned short Bs[272 * 40];
    int t = threadIdx.x;
    int m0 = blockIdx.x * 128;
    int lane = t & 63, wm = t >> 6;
    int quad = lane >> 4, l16 = lane & 15;

    floatx4 acc[2][17];
#pragma unroll
    for (int i = 0; i < 2; ++i)
#pragma unroll
        for (int j = 0; j < 17; ++j) acc[i][j] = (floatx4){0.f, 0.f, 0.f, 0.f};

    int arow = t >> 1, ak = (t & 1) * 16;
    int grow = m0 + arow;
    const float* xrow = X + (size_t)grow * 256 + ak;

    for (int k0 = 0; k0 < 256; k0 += 32) {
        float4 v0 = make_float4(0.f, 0.f, 0.f, 0.f), v1 = v0, v2 = v0, v3 = v0;
        if (grow < N_NODES) {
            v0 = *(const float4*)(xrow + k0 + 0);
            v1 = *(const float4*)(xrow + k0 + 4);
            v2 = *(const float4*)(xrow + k0 + 8);
            v3 = *(const float4*)(xrow + k0 + 12);
        }
        uint4 p0, p1;
        p0.x = pack2(v0.x, v0.y); p0.y = pack2(v0.z, v0.w);
        p0.z = pack2(v1.x, v1.y); p0.w = pack2(v1.z, v1.w);
        p1.x = pack2(v2.x, v2.y); p1.y = pack2(v2.z, v2.w);
        p1.z = pack2(v3.x, v3.y); p1.w = pack2(v3.z, v3.w);
        *(uint4*)&As[arow * 40 + ak] = p0;
        *(uint4*)&As[arow * 40 + ak + 8] = p1;
#pragma unroll
        for (int i = 0; i < 5; ++i) {
            int ch = t + i * 256;
            if (ch < 1088) {
                int row = ch >> 2, off = (ch & 3) * 8;
                *(uint4*)&Bs[row * 40 + off] = *(const uint4*)(BT + row * 256 + k0 + off);
            }
        }
        __syncthreads();

        short8 a0 = *(const short8*)&As[(wm * 32 + l16) * 40 + quad * 8];
        short8 a1 = *(const short8*)&As[(wm * 32 + 16 + l16) * 40 + quad * 8];
#pragma unroll
        for (int nf = 0; nf < 17; ++nf) {
            short8 bb = *(const short8*)&Bs[(nf * 16 + l16) * 40 + quad * 8];
            acc[0][nf] = __builtin_amdgcn_mfma_f32_16x16x32_bf16(a0, bb, acc[0][nf], 0, 0, 0);
            acc[1][nf] = __builtin_amdgcn_mfma_f32_16x16x32_bf16(a1, bb, acc[1][nf], 0, 0, 0);
        }
        __syncthreads();
    }

#pragma unroll
    for (int mf = 0; mf < 2; ++mf) {
#pragma unroll
        for (int r = 0; r < 4; ++r) {
            int row = m0 + wm * 32 + mf * 16 + quad * 4 + r;
            if (row < N_NODES && l16 < 8) {
                float v = acc[mf][16][r];
                if (l16 < 4) el[row * 4 + l16] = v;
                else er[row * 4 + (l16 - 4)] = v;
            }
        }
    }

    unsigned short* scr = Bs + wm * 1536;
    int half = lane >> 5, l32 = lane & 31;
    int rrow = l32 >> 1, coff = (l32 & 1) * 8;
#pragma unroll
    for (int mf = 0; mf < 2; ++mf) {
#pragma unroll
        for (int p = 0; p < 8; ++p) {
            unsigned short* base = scr + (p & 1) * 768;
#pragma unroll
            for (int fr = 0; fr < 2; ++fr) {
                int nf = 2 * p + fr;
                unsigned short* fb = base + fr * 384;
#pragma unroll
                for (int r = 0; r < 4; ++r)
                    fb[(quad * 4 + r) * 24 + l16] = f2b(acc[mf][nf][r]);
            }
            uint4 val = *(const uint4*)(base + half * 384 + rrow * 24 + coff);
            int row = m0 + wm * 32 + mf * 16 + rrow;
            int nf = 2 * p + half;
            if (row < N_NODES)
                *(uint4*)&C[(size_t)row * 256 + nf * 16 + coff] = val;
        }
    }
}

// ---------------- layer-1 aggregation: quarter-wave per edge, 2x unroll ----------------
__global__ void agg1_kernel(const unsigned short* __restrict__ feat1,
                            const float* __restrict__ el, const float* __restrict__ er,
                            const int* __restrict__ row_ptr, const int* __restrict__ csr_src,
                            const float* __restrict__ b1, unsigned short* __restrict__ h1b) {
    int wave = threadIdx.x >> 6, lane = threadIdx.x & 63;
    int n = blockIdx.x * 4 + wave;
    if (n >= N_NODES) return;
    int q = lane >> 4, l16 = lane & 15;
    int h = l16 >> 2;
    float er_h = er[n * 4 + h];
    int start = row_ptr[n], end = row_ptr[n + 1];

    float acc[16];
#pragma unroll
    for (int j = 0; j < 16; ++j) acc[j] = 0.f;
    float denom = 0.f;

    int i = start + q;
    for (; i + 4 < end; i += 8) {
        int s0 = csr_src[i];
        int s1 = csr_src[i + 4];
        float ex0 = __expf(leaky(el[s0 * 4 + h] + er_h));
        float ex1 = __expf(leaky(el[s1 * 4 + h] + er_h));
        const uint4* p0 = (const uint4*)(feat1 + (size_t)s0 * 256 + l16 * 16);
        const uint4* p1 = (const uint4*)(feat1 + (size_t)s1 * 256 + l16 * 16);
        uint4 a0 = p0[0], a1 = p0[1];
        uint4 b0 = p1[0], b1v = p1[1];
        denom += ex0 + ex1;
        acc[0]  = fmaf(blo(a0.x), ex0, acc[0]);   acc[0]  = fmaf(blo(b0.x), ex1, acc[0]);
        acc[1]  = fmaf(bhi(a0.x), ex0, acc[1]);   acc[1]  = fmaf(bhi(b0.x), ex1, acc[1]);
        acc[2]  = fmaf(blo(a0.y), ex0, acc[2]);   acc[2]  = fmaf(blo(b0.y), ex1, acc[2]);
        acc[3]  = fmaf(bhi(a0.y), ex0, acc[3]);   acc[3]  = fmaf(bhi(b0.y), ex1, acc[3]);
        acc[4]  = fmaf(blo(a0.z), ex0, acc[4]);   acc[4]  = fmaf(blo(b0.z), ex1, acc[4]);
        acc[5]  = fmaf(bhi(a0.z), ex0, acc[5]);   acc[5]  = fmaf(bhi(b0.z), ex1, acc[5]);
        acc[6]  = fmaf(blo(a0.w), ex0, acc[6]);   acc[6]  = fmaf(blo(b0.w), ex1, acc[6]);
        acc[7]  = fmaf(bhi(a0.w), ex0, acc[7]);   acc[7]  = fmaf(bhi(b0.w), ex1, acc[7]);
        acc[8]  = fmaf(blo(a1.x), ex0, acc[8]);   acc[8]  = fmaf(blo(b1v.x), ex1, acc[8]);
        acc[9]  = fmaf(bhi(a1.x), ex0, acc[9]);   acc[9]  = fmaf(bhi(b1v.x), ex1, acc[9]);
        acc[10] = fmaf(blo(a1.y), ex0, acc[10]);  acc[10] = fmaf(blo(b1v.y), ex1, acc[10]);
        acc[11] = fmaf(bhi(a1.y), ex0, acc[11]);  acc[11] = fmaf(bhi(b1v.y), ex1, acc[11]);
        acc[12] = fmaf(blo(a1.z), ex0, acc[12]);  acc[12] = fmaf(blo(b1v.z), ex1, acc[12]);
        acc[13] = fmaf(bhi(a1.z), ex0, acc[13]);  acc[13] = fmaf(bhi(b1v.z), ex1, acc[13]);
        acc[14] = fmaf(blo(a1.w), ex0, acc[14]);  acc[14] = fmaf(blo(b1v.w), ex1, acc[14]);
        acc[15] = fmaf(bhi(a1.w), ex0, acc[15]);  acc[15] = fmaf(bhi(b1v.w), ex1, acc[15]);
    }
    if (i < end) {
        int s = csr_src[i];
        float ex = __expf(leaky(el[s * 4 + h] + er_h));
        const uint4* p = (const uint4*)(feat1 + (size_t)s * 256 + l16 * 16);
        uint4 u0 = p[0], u1 = p[1];
        denom += ex;
        acc[0]  = fmaf(blo(u0.x), ex, acc[0]);
        acc[1]  = fmaf(bhi(u0.x), ex, acc[1]);
        acc[2]  = fmaf(blo(u0.y), ex, acc[2]);
        acc[3]  = fmaf(bhi(u0.y), ex, acc[3]);
        acc[4]  = fmaf(blo(u0.z), ex, acc[4]);
        acc[5]  = fmaf(bhi(u0.z), ex, acc[5]);
        acc[6]  = fmaf(blo(u0.w), ex, acc[6]);
        acc[7]  = fmaf(bhi(u0.w), ex, acc[7]);
        acc[8]  = fmaf(blo(u1.x), ex, acc[8]);
        acc[9]  = fmaf(bhi(u1.x), ex, acc[9]);
        acc[10] = fmaf(blo(u1.y), ex, acc[10]);
        acc[11] = fmaf(bhi(u1.y), ex, acc[11]);
        acc[12] = fmaf(blo(u1.z), ex, acc[12]);
        acc[13] = fmaf(bhi(u1.z), ex, acc[13]);
        acc[14] = fmaf(blo(u1.w), ex, acc[14]);
        acc[15] = fmaf(bhi(u1.w), ex, acc[15]);
    }
#pragma unroll
    for (int j = 0; j < 16; ++j) {
        acc[j] += __shfl_xor(acc[j], 16);
        acc[j] += __shfl_xor(acc[j], 32);
    }
    denom += __shfl_xor(denom, 16);
    denom += __shfl_xor(denom, 32);

    if (q == 0) {
        float inv = (end > start) ? 1.f / denom : 0.f;
        float o[16];
#pragma unroll
        for (int j = 0; j < 16; j += 4) {
            float4 b4 = *(const float4*)&b1[l16 * 16 + j];
            o[j + 0] = fmaf(acc[j + 0], inv, b4.x);
            o[j + 1] = fmaf(acc[j + 1], inv, b4.y);
            o[j + 2] = fmaf(acc[j + 2], inv, b4.z);
            o[j + 3] = fmaf(acc[j + 3], inv, b4.w);
        }
#pragma unroll
        for (int j = 0; j < 16; ++j) o[j] = o[j] > 0.f ? o[j] : __expf(o[j]) - 1.f;
        uint4 pa, pb;
        pa.x = pack2(o[0], o[1]);   pa.y = pack2(o[2], o[3]);
        pa.z = pack2(o[4], o[5]);   pa.w = pack2(o[6], o[7]);
        pb.x = pack2(o[8], o[9]);   pb.y = pack2(o[10], o[11]);
        pb.z = pack2(o[12], o[13]); pb.w = pack2(o[14], o[15]);
        uint4* dstp = (uint4*)(h1b + (size_t)n * 256 + l16 * 16);
        dstp[0] = pa;
        dstp[1] = pb;
    }
}

// ---------------- GEMM2 (bf16 MFMA, no LDS) + fused el2/er2 ----------------
__global__ __launch_bounds__(256) void gemm2_mfma_kernel(
        const unsigned short* __restrict__ h1b, const unsigned short* __restrict__ W2T,
        const float* __restrict__ al2, const float* __restrict__ ar2,
        float* __restrict__ feat2, float* __restrict__ el2, float* __restrict__ er2) {
    int wave = threadIdx.x >> 6, lane = threadIdx.x & 63;
    int l16 = lane & 15, quad = lane >> 4;
    int row0 = (blockIdx.x * 4 + wave) * 16;
    if (row0 >= N_NODES) return;
    floatx4 acc = (floatx4){0.f, 0.f, 0.f, 0.f};
    const unsigned short* arow = h1b + (size_t)(row0 + l16) * 256 + quad * 8;
    const unsigned short* brow = W2T + (size_t)l16 * 256 + quad * 8;
#pragma unroll
    for (int k0 = 0; k0 < 256; k0 += 32) {
        short8 a = *(const short8*)(arow + k0);
        short8 b = *(const short8*)(brow + k0);
        acc = __builtin_amdgcn_mfma_f32_16x16x32_bf16(a, b, acc, 0, 0, 0);
    }
    float a2 = al2[l16], r2 = ar2[l16];
#pragma unroll
    for (int r = 0; r < 4; ++r) {
        int row = row0 + quad * 4 + r;
        float v = acc[r];
        feat2[row * 16 + l16] = v;
        float pl = v * a2, pr = v * r2;
#pragma unroll
        for (int off = 1; off < 16; off <<= 1) {
            pl += __shfl_xor(pl, off);
            pr += __shfl_xor(pr, off);
        }
        if (l16 == 0) {
            el2[row] = pl;
            er2[row] = pr;
        }
    }
}

// ---------------- layer-2 aggregation + log_softmax, 2x unroll ----------------
__global__ void agg2_kernel(const float* __restrict__ feat2, const float* __restrict__ el2,
                            const float* __restrict__ er2, const int* __restrict__ row_ptr,
                            const int* __restrict__ csr_src, const float* __restrict__ b2,
                            float* __restrict__ out) {
    int wave = threadIdx.x >> 6, lane = threadIdx.x & 63;
    int n = blockIdx.x * 4 + wave;
    if (n >= N_NODES) return;
    int start = row_ptr[n], end = row_ptr[n + 1];
    float ern = er2[n];
    int eo = lane >> 4, c = lane & 15;
    float acc = 0.f, denom = 0.f;
    int i = start + eo;
    for (; i + 4 < end; i += 8) {
        int s0 = csr_src[i], s1 = csr_src[i + 4];
        float ex0 = __expf(leaky(el2[s0] + ern));
        float ex1 = __expf(leaky(el2[s1] + ern));
        float f0 = feat2[s0 * 16 + c], f1 = feat2[s1 * 16 + c];
        denom += ex0 + ex1;
        acc = fmaf(f0, ex0, acc);
        acc = fmaf(f1, ex1, acc);
    }
    if (i < end) {
        int s = csr_src[i];
        float ex = __expf(leaky(el2[s] + ern));
        denom += ex;
        acc = fmaf(feat2[s * 16 + c], ex, acc);
    }
    acc += __shfl_xor(acc, 16);
    acc += __shfl_xor(acc, 32);
    denom += __shfl_xor(denom, 16);
    denom += __shfl_xor(denom, 32);
    float v = ((end > start) ? acc / denom : 0.f) + b2[c];
    float mx = v;
#pragma unroll
    for (int off = 1; off < 16; off <<= 1) mx = fmaxf(mx, __shfl_xor(mx, off));
    float ex2 = __expf(v - mx);
    float s2 = ex2;
#pragma unroll
    for (int off = 1; off < 16; off <<= 1) s2 += __shfl_xor(s2, off);
    float res = v - mx - logf(s2);
    if (lane < 16) out[n * 16 + lane] = res;
}

// ---------------- launch ----------------
extern "C" void kernel_launch(void* const* d_in, const int* in_sizes, int n_in,
                              void* d_out, int out_size, void* d_ws, size_t ws_size,
                              hipStream_t stream) {
    const float* x   = (const float*)d_in[0];
    const int*   src = (const int*)d_in[1];
    const int*   dst = (const int*)d_in[2];
    const float* W1  = (const float*)d_in[3];
    const float* al1 = (const float*)d_in[4];
    const float* ar1 = (const float*)d_in[5];
    const float* b1  = (const float*)d_in[6];
    const float* W2  = (const float*)d_in[7];
    const float* al2 = (const float*)d_in[8];
    const float* ar2 = (const float*)d_in[9];
    const float* b2  = (const float*)d_in[10];
    float* out = (float*)d_out;

    char* ws = (char*)d_ws;
    size_t off = 0;
    auto alloc = [&](size_t bytes) -> void* {
        void* p = ws + off;
        off += (bytes + 255) & ~(size_t)255;
        return p;
    };
    unsigned short* W1E   = (unsigned short*)alloc((size_t)272 * 256 * 2);
    unsigned short* W2T   = (unsigned short*)alloc((size_t)16 * 256 * 2);
    unsigned short* feat1 = (unsigned short*)alloc((size_t)N_NODES * 256 * 2);
    unsigned short* h1b   = (unsigned short*)alloc((size_t)N_NODES * 256 * 2);
    float* feat2   = (float*)alloc((size_t)N_NODES * 16 * 4);
    float* el1     = (float*)alloc((size_t)N_NODES * 4 * 4);
    float* er1     = (float*)alloc((size_t)N_NODES * 4 * 4);
    float* el2     = (float*)alloc((size_t)N_NODES * 4);
    float* er2     = (float*)alloc((size_t)N_NODES * 4);
    int*   bhist   = (int*)alloc((size_t)NSCAN * 4);
    int*   partial = (int*)alloc((size_t)NSCAN * 4);
    int*   scanned = (int*)alloc((size_t)NSCAN * 4);
    int*   bsum    = (int*)alloc((size_t)256 * 4);
    int*   row_ptr = (int*)alloc((size_t)NP1 * 4);
    int*   ebuf    = (int*)alloc((size_t)N_EDGES * 4);
    int*   csr_src = (int*)alloc((size_t)N_EDGES * 4);

    dim3 b256(256);
    p1_kernel<<<NBLK + 21, b256, 0, stream>>>(dst, bhist, W1, W2, al1, ar1, W1E, W2T);
    scanA_kernel<<<NSCB, b256, 0, stream>>>(bhist, partial, bsum);
    scanB_kernel<<<NSCB, b256, 0, stream>>>(partial, bsum, scanned);
    p2_kernel<<<NBLK, b256, 0, stream>>>(src, dst, scanned, ebuf);
    p3_kernel<<<NBUCK, b256, 0, stream>>>(scanned, ebuf, row_ptr, csr_src);

    gemm1_mfma_kernel<<<(N_NODES + 127) / 128, b256, 0, stream>>>(x, W1E, feat1, el1, er1);
    agg1_kernel<<<(N_NODES + 3) / 4, b256, 0, stream>>>(feat1, el1, er1, row_ptr, csr_src, b1, h1b);

    gemm2_mfma_kernel<<<(N_NODES + 63) / 64, b256, 0, stream>>>(h1b, W2T, al2, ar2, feat2, el2, er2);
    agg2_kernel<<<(N_NODES + 3) / 4, b256, 0, stream>>>(feat2, el2, er2, row_ptr, csr_src, b2, out);
}

// Round 8
// 253.068 us; speedup vs baseline: 1.3198x; 1.0941x over previous
//
#include <hip/hip_runtime.h>
#include <hip/hip_bf16.h>

#define N_NODES 50000
#define NP1     50001
#define N_EDGES 800000
#define NFEAT   256
#define NHID    64
#define HEADS   4
#define NCLASS  16
#define NEG_SLOPE 0.2f

#define NBLK  782                 // edge blocks (1024 edges each)
#define NBUCK 196                 // buckets of 256 nodes (dst >> 8)
#define NSCAN (NBUCK * NBLK)      // 153272
#define NSCB  150                 // ceil(NSCAN / 1024)

typedef __attribute__((ext_vector_type(8))) short short8;
typedef __attribute__((ext_vector_type(4))) float floatx4;
typedef __attribute__((ext_vector_type(2))) float floatx2;

__device__ __forceinline__ float blo(unsigned int u) { return __uint_as_float(u << 16); }
__device__ __forceinline__ float bhi(unsigned int u) { return __uint_as_float(u & 0xffff0000u); }
__device__ __forceinline__ unsigned short f2b(float f) {
    unsigned int x = __float_as_uint(f);
    unsigned int r = x + 0x7fffu + ((x >> 16) & 1u);
    return (unsigned short)(r >> 16);
}
__device__ __forceinline__ unsigned int pack2(float a, float b) {
    return (unsigned int)f2b(a) | ((unsigned int)f2b(b) << 16);
}
__device__ __forceinline__ float leaky(float x) { return fmaxf(x, NEG_SLOPE * x); }

// unpack 16 fp8 (uint4) and accumulate acc[j] += f[j] * ex  (HW cvt, 2 vals/instr)
__device__ __forceinline__ void fp8acc(uint4 u, float ex, float* acc) {
    floatx2 p;
    p = __builtin_amdgcn_cvt_pk_f32_fp8(u.x, 0); acc[0]  = fmaf(p[0], ex, acc[0]);  acc[1]  = fmaf(p[1], ex, acc[1]);
    p = __builtin_amdgcn_cvt_pk_f32_fp8(u.x, 1); acc[2]  = fmaf(p[0], ex, acc[2]);  acc[3]  = fmaf(p[1], ex, acc[3]);
    p = __builtin_amdgcn_cvt_pk_f32_fp8(u.y, 0); acc[4]  = fmaf(p[0], ex, acc[4]);  acc[5]  = fmaf(p[1], ex, acc[5]);
    p = __builtin_amdgcn_cvt_pk_f32_fp8(u.y, 1); acc[6]  = fmaf(p[0], ex, acc[6]);  acc[7]  = fmaf(p[1], ex, acc[7]);
    p = __builtin_amdgcn_cvt_pk_f32_fp8(u.z, 0); acc[8]  = fmaf(p[0], ex, acc[8]);  acc[9]  = fmaf(p[1], ex, acc[9]);
    p = __builtin_amdgcn_cvt_pk_f32_fp8(u.z, 1); acc[10] = fmaf(p[0], ex, acc[10]); acc[11] = fmaf(p[1], ex, acc[11]);
    p = __builtin_amdgcn_cvt_pk_f32_fp8(u.w, 0); acc[12] = fmaf(p[0], ex, acc[12]); acc[13] = fmaf(p[1], ex, acc[13]);
    p = __builtin_amdgcn_cvt_pk_f32_fp8(u.w, 1); acc[14] = fmaf(p[0], ex, acc[14]); acc[15] = fmaf(p[1], ex, acc[15]);
}

// ---------------- P1: per-block bucket histogram + fused weight prep ----------------
__global__ __launch_bounds__(256) void p1_kernel(
        const int* __restrict__ dst, int* __restrict__ bhist,
        const float* __restrict__ W1, const float* __restrict__ W2,
        const float* __restrict__ al1, const float* __restrict__ ar1,
        unsigned short* __restrict__ W1E, unsigned short* __restrict__ W2T) {
    __shared__ float tile[64][65];
    __shared__ int hist[NBUCK];
    int b = blockIdx.x, t = threadIdx.x;
    if (b < NBLK) {
        if (t < NBUCK) hist[t] = 0;
        __syncthreads();
        int e = (b * 256 + t) * 4;
        if (e < N_EDGES) {
            int4 d = *(const int4*)&dst[e];
            atomicAdd(&hist[d.x >> 8], 1);
            atomicAdd(&hist[d.y >> 8], 1);
            atomicAdd(&hist[d.z >> 8], 1);
            atomicAdd(&hist[d.w >> 8], 1);
        }
        __syncthreads();
        if (t < NBUCK) bhist[t * NBLK + b] = hist[t];
        return;
    }
    int pb = b - NBLK;
    if (pb < 16) {
        int tk = (pb & 3) * 64, tn = (pb >> 2) * 64;
        int tx = t & 63, ty = t >> 6;
#pragma unroll
        for (int r = 0; r < 16; ++r) {
            int row = ty * 16 + r;
            tile[row][tx] = W1[(tk + row) * 256 + tn + tx];
        }
        __syncthreads();
#pragma unroll
        for (int r = 0; r < 16; ++r) {
            int row = ty * 16 + r;
            W1E[(tn + row) * 256 + tk + tx] = f2b(tile[tx][row]);
        }
    } else if (pb < 20) {
        int h = pb - 16;
        int w = t >> 6, lane = t & 63;
        float alv = al1[h * 64 + lane];
        float arv = ar1[h * 64 + lane];
        for (int k = w; k < 256; k += 4) {
            float wv = W1[k * 256 + h * 64 + lane];
            float sl = wv * alv, sr = wv * arv;
#pragma unroll
            for (int off = 1; off < 64; off <<= 1) {
                sl += __shfl_xor(sl, off);
                sr += __shfl_xor(sr, off);
            }
            if (lane == 0) {
                W1E[(256 + h) * 256 + k] = f2b(sl);
                W1E[(260 + h) * 256 + k] = f2b(sr);
            }
        }
    } else {
        int n = t >> 4, k0 = (t & 15) * 16;
#pragma unroll
        for (int j = 0; j < 16; ++j)
            W2T[n * 256 + k0 + j] = f2b(W2[(k0 + j) * 16 + n]);
#pragma unroll
        for (int j = 0; j < 8; ++j)
            W1E[264 * 256 + j * 256 + t] = 0;
    }
}

// ---------------- scanA: per-chunk (1024) exclusive scan of bhist ----------------
__global__ __launch_bounds__(256) void scanA_kernel(const int* __restrict__ bhist,
                                                    int* __restrict__ partial,
                                                    int* __restrict__ bsum) {
    __shared__ int wsum[4];
    int t = threadIdx.x;
    int base = blockIdx.x * 1024 + t * 4;
    int v0 = (base + 0 < NSCAN) ? bhist[base + 0] : 0;
    int v1 = (base + 1 < NSCAN) ? bhist[base + 1] : 0;
    int v2 = (base + 2 < NSCAN) ? bhist[base + 2] : 0;
    int v3 = (base + 3 < NSCAN) ? bhist[base + 3] : 0;
    int s = v0 + v1 + v2 + v3;
    int lane = t & 63, w = t >> 6;
    int incl = s;
#pragma unroll
    for (int off = 1; off < 64; off <<= 1) {
        int x = __shfl_up(incl, off);
        if (lane >= off) incl += x;
    }
    if (lane == 63) wsum[w] = incl;
    __syncthreads();
    int woff = 0;
    for (int k = 0; k < w; ++k) woff += wsum[k];
    int excl = woff + incl - s;
    if (base + 0 < NSCAN) partial[base + 0] = excl;
    if (base + 1 < NSCAN) partial[base + 1] = excl + v0;
    if (base + 2 < NSCAN) partial[base + 2] = excl + v0 + v1;
    if (base + 3 < NSCAN) partial[base + 3] = excl + v0 + v1 + v2;
    if (t == 255) bsum[blockIdx.x] = woff + incl;
}

// ---------------- P2: scatter edges into bucket-sorted ebuf (inline bsum scan) ----------------
__global__ __launch_bounds__(256) void p2_kernel(const int* __restrict__ src,
                                                 const int* __restrict__ dst,
                                                 const int* __restrict__ partial,
                                                 const int* __restrict__ bsum,
                                                 int* __restrict__ ebuf) {
    __shared__ int wsum[4];
    __shared__ int sb[256];
    __shared__ int bs[NBUCK];
    int b = blockIdx.x, t = threadIdx.x;
    // inline exclusive scan of bsum[0..NSCB)
    {
        int v = (t < NSCB) ? bsum[t] : 0;
        int lane = t & 63, w = t >> 6;
        int incl = v;
#pragma unroll
        for (int off = 1; off < 64; off <<= 1) {
            int x = __shfl_up(incl, off);
            if (lane >= off) incl += x;
        }
        if (lane == 63) wsum[w] = incl;
        __syncthreads();
        int woff = 0;
        for (int k = 0; k < w; ++k) woff += wsum[k];
        sb[t] = woff + incl - v;
    }
    __syncthreads();
    if (t < NBUCK) {
        int idx = t * NBLK + b;
        bs[t] = partial[idx] + sb[idx >> 10];
    }
    __syncthreads();
    int e = (b * 256 + t) * 4;
    if (e < N_EDGES) {
        int4 d = *(const int4*)&dst[e];
        int4 s = *(const int4*)&src[e];
        int p0 = atomicAdd(&bs[d.x >> 8], 1);
        ebuf[p0] = (s.x << 8) | (d.x & 255);
        int p1 = atomicAdd(&bs[d.y >> 8], 1);
        ebuf[p1] = (s.y << 8) | (d.y & 255);
        int p2 = atomicAdd(&bs[d.z >> 8], 1);
        ebuf[p2] = (s.z << 8) | (d.z & 255);
        int p3 = atomicAdd(&bs[d.w >> 8], 1);
        ebuf[p3] = (s.w << 8) | (d.w & 255);
    }
}

// ---------------- P3: per-bucket CSR finalize (inline bsum scan) ----------------
__global__ __launch_bounds__(256) void p3_kernel(const int* __restrict__ partial,
                                                 const int* __restrict__ bsum,
                                                 const int* __restrict__ ebuf,
                                                 int* __restrict__ row_ptr,
                                                 int* __restrict__ csr_src) {
    __shared__ int lcnt[256];
    __shared__ int loff[256];
    __shared__ int wsum[4];
    __shared__ int sb[256];
    int b = blockIdx.x, t = threadIdx.x;
    {
        int v = (t < NSCB) ? bsum[t] : 0;
        int lane = t & 63, w = t >> 6;
        int incl = v;
#pragma unroll
        for (int off = 1; off < 64; off <<= 1) {
            int x = __shfl_up(incl, off);
            if (lane >= off) incl += x;
        }
        if (lane == 63) wsum[w] = incl;
        __syncthreads();
        int woff = 0;
        for (int k = 0; k < w; ++k) woff += wsum[k];
        sb[t] = woff + incl - v;
    }
    __syncthreads();
    int i0 = b * NBLK;
    int base = partial[i0] + sb[i0 >> 10];
    int endb;
    if (b == NBUCK - 1) endb = N_EDGES;
    else {
        int i1 = (b + 1) * NBLK;
        endb = partial[i1] + sb[i1 >> 10];
    }
    lcnt[t] = 0;
    __syncthreads();
    for (int i = base + t; i < endb; i += 256)
        atomicAdd(&lcnt[ebuf[i] & 255], 1);
    __syncthreads();
    int v = lcnt[t];
    int lane = t & 63, w = t >> 6;
    int incl = v;
#pragma unroll
    for (int off = 1; off < 64; off <<= 1) {
        int x = __shfl_up(incl, off);
        if (lane >= off) incl += x;
    }
    if (lane == 63) wsum[w] = incl;
    __syncthreads();
    int woff = 0;
    for (int k = 0; k < w; ++k) woff += wsum[k];
    int excl = woff + incl - v;
    loff[t] = base + excl;
    int node = b * 256 + t;
    if (node < NP1) row_ptr[node] = base + excl;
    __syncthreads();
    for (int i = base + t; i < endb; i += 256) {
        int p = ebuf[i];
        int pos = atomicAdd(&loff[p & 255], 1);
        csr_src[pos] = p >> 8;
    }
}

// ---------------- GEMM1 (bf16 MFMA): [feat1(fp8) | el | er] = x @ [W1 | Wel | Wer] ----------------
__global__ __launch_bounds__(256, 2) void gemm1_mfma_kernel(
        const float* __restrict__ X, const unsigned short* __restrict__ BT,
        unsigned char* __restrict__ C, float* __restrict__ el, float* __restrict__ er) {
    __shared__ __align__(16) unsigned short As[128 * 40];
    __shared__ __align__(16) unsigned short Bs[272 * 40];
    int t = threadIdx.x;
    int m0 = blockIdx.x * 128;
    int lane = t & 63, wm = t >> 6;
    int quad = lane >> 4, l16 = lane & 15;

    floatx4 acc[2][17];
#pragma unroll
    for (int i = 0; i < 2; ++i)
#pragma unroll
        for (int j = 0; j < 17; ++j) acc[i][j] = (floatx4){0.f, 0.f, 0.f, 0.f};

    int arow = t >> 1, ak = (t & 1) * 16;
    int grow = m0 + arow;
    const float* xrow = X + (size_t)grow * 256 + ak;

    for (int k0 = 0; k0 < 256; k0 += 32) {
        float4 v0 = make_float4(0.f, 0.f, 0.f, 0.f), v1 = v0, v2 = v0, v3 = v0;
        if (grow < N_NODES) {
            v0 = *(const float4*)(xrow + k0 + 0);
            v1 = *(const float4*)(xrow + k0 + 4);
            v2 = *(const float4*)(xrow + k0 + 8);
            v3 = *(const float4*)(xrow + k0 + 12);
        }
        uint4 p0, p1;
        p0.x = pack2(v0.x, v0.y); p0.y = pack2(v0.z, v0.w);
        p0.z = pack2(v1.x, v1.y); p0.w = pack2(v1.z, v1.w);
        p1.x = pack2(v2.x, v2.y); p1.y = pack2(v2.z, v2.w);
        p1.z = pack2(v3.x, v3.y); p1.w = pack2(v3.z, v3.w);
        *(uint4*)&As[arow * 40 + ak] = p0;
        *(uint4*)&As[arow * 40 + ak + 8] = p1;
#pragma unroll
        for (int i = 0; i < 5; ++i) {
            int ch = t + i * 256;
            if (ch < 1088) {
                int row = ch >> 2, off = (ch & 3) * 8;
                *(uint4*)&Bs[row * 40 + off] = *(const uint4*)(BT + row * 256 + k0 + off);
            }
        }
        __syncthreads();

        short8 a0 = *(const short8*)&As[(wm * 32 + l16) * 40 + quad * 8];
        short8 a1 = *(const short8*)&As[(wm * 32 + 16 + l16) * 40 + quad * 8];
#pragma unroll
        for (int nf = 0; nf < 17; ++nf) {
            short8 bb = *(const short8*)&Bs[(nf * 16 + l16) * 40 + quad * 8];
            acc[0][nf] = __builtin_amdgcn_mfma_f32_16x16x32_bf16(a0, bb, acc[0][nf], 0, 0, 0);
            acc[1][nf] = __builtin_amdgcn_mfma_f32_16x16x32_bf16(a1, bb, acc[1][nf], 0, 0, 0);
        }
        __syncthreads();
    }

#pragma unroll
    for (int mf = 0; mf < 2; ++mf) {
#pragma unroll
        for (int r = 0; r < 4; ++r) {
            int row = m0 + wm * 32 + mf * 16 + quad * 4 + r;
            if (row < N_NODES && l16 < 8) {
                float v = acc[mf][16][r];
                if (l16 < 4) el[row * 4 + l16] = v;
                else er[row * 4 + (l16 - 4)] = v;
            }
        }
    }

    unsigned short* scr = Bs + wm * 1536;
    int half = lane >> 5, l32 = lane & 31;
    int rrow = l32 >> 1, coff = (l32 & 1) * 8;
#pragma unroll
    for (int mf = 0; mf < 2; ++mf) {
#pragma unroll
        for (int p = 0; p < 8; ++p) {
            unsigned short* base = scr + (p & 1) * 768;
#pragma unroll
            for (int fr = 0; fr < 2; ++fr) {
                int nf = 2 * p + fr;
                unsigned short* fb = base + fr * 384;
#pragma unroll
                for (int r = 0; r < 4; ++r)
                    fb[(quad * 4 + r) * 24 + l16] = f2b(acc[mf][nf][r]);
            }
            uint4 val = *(const uint4*)(base + half * 384 + rrow * 24 + coff);
            int row = m0 + wm * 32 + mf * 16 + rrow;
            int nf = 2 * p + half;
            if (row < N_NODES) {
                float f0 = blo(val.x), f1 = bhi(val.x), f2 = blo(val.y), f3 = bhi(val.y);
                float f4 = blo(val.z), f5 = bhi(val.z), f6 = blo(val.w), f7 = bhi(val.w);
                int lo = __builtin_amdgcn_cvt_pk_fp8_f32(f0, f1, 0, 0);
                lo = __builtin_amdgcn_cvt_pk_fp8_f32(f2, f3, lo, 1);
                int hi = __builtin_amdgcn_cvt_pk_fp8_f32(f4, f5, 0, 0);
                hi = __builtin_amdgcn_cvt_pk_fp8_f32(f6, f7, hi, 1);
                uint2 o;
                o.x = (unsigned int)lo;
                o.y = (unsigned int)hi;
                *(uint2*)&C[(size_t)row * 256 + nf * 16 + coff] = o;
            }
        }
    }
}

// ---------------- layer-1 aggregation: fp8 gather, quarter-wave per edge, 2x unroll ----------------
__global__ void agg1_kernel(const unsigned char* __restrict__ feat1,
                            const float* __restrict__ el, const float* __restrict__ er,
                            const int* __restrict__ row_ptr, const int* __restrict__ csr_src,
                            const float* __restrict__ b1, unsigned short* __restrict__ h1b) {
    int wave = threadIdx.x >> 6, lane = threadIdx.x & 63;
    int n = blockIdx.x * 4 + wave;
    if (n >= N_NODES) return;
    int q = lane >> 4, l16 = lane & 15;
    int h = l16 >> 2;
    float er_h = er[n * 4 + h];
    int start = row_ptr[n], end = row_ptr[n + 1];

    float acc[16];
#pragma unroll
    for (int j = 0; j < 16; ++j) acc[j] = 0.f;
    float denom = 0.f;

    int i = start + q;
    for (; i + 4 < end; i += 8) {
        int s0 = csr_src[i];
        int s1 = csr_src[i + 4];
        float ex0 = __expf(leaky(el[s0 * 4 + h] + er_h));
        float ex1 = __expf(leaky(el[s1 * 4 + h] + er_h));
        uint4 a = *(const uint4*)(feat1 + (size_t)s0 * 256 + l16 * 16);
        uint4 b = *(const uint4*)(feat1 + (size_t)s1 * 256 + l16 * 16);
        denom += ex0 + ex1;
        fp8acc(a, ex0, acc);
        fp8acc(b, ex1, acc);
    }
    if (i < end) {
        int s = csr_src[i];
        float ex = __expf(leaky(el[s * 4 + h] + er_h));
        uint4 u = *(const uint4*)(feat1 + (size_t)s * 256 + l16 * 16);
        denom += ex;
        fp8acc(u, ex, acc);
    }
#pragma unroll
    for (int j = 0; j < 16; ++j) {
        acc[j] += __shfl_xor(acc[j], 16);
        acc[j] += __shfl_xor(acc[j], 32);
    }
    denom += __shfl_xor(denom, 16);
    denom += __shfl_xor(denom, 32);

    if (q == 0) {
        float inv = (end > start) ? 1.f / denom : 0.f;
        float o[16];
#pragma unroll
        for (int j = 0; j < 16; j += 4) {
            float4 b4 = *(const float4*)&b1[l16 * 16 + j];
            o[j + 0] = fmaf(acc[j + 0], inv, b4.x);
            o[j + 1] = fmaf(acc[j + 1], inv, b4.y);
            o[j + 2] = fmaf(acc[j + 2], inv, b4.z);
            o[j + 3] = fmaf(acc[j + 3], inv, b4.w);
        }
#pragma unroll
        for (int j = 0; j < 16; ++j) o[j] = o[j] > 0.f ? o[j] : __expf(o[j]) - 1.f;
        uint4 pa, pb;
        pa.x = pack2(o[0], o[1]);   pa.y = pack2(o[2], o[3]);
        pa.z = pack2(o[4], o[5]);   pa.w = pack2(o[6], o[7]);
        pb.x = pack2(o[8], o[9]);   pb.y = pack2(o[10], o[11]);
        pb.z = pack2(o[12], o[13]); pb.w = pack2(o[14], o[15]);
        uint4* dstp = (uint4*)(h1b + (size_t)n * 256 + l16 * 16);
        dstp[0] = pa;
        dstp[1] = pb;
    }
}

// ---------------- GEMM2 (bf16 MFMA, no LDS) + fused el2/er2 ----------------
__global__ __launch_bounds__(256) void gemm2_mfma_kernel(
        const unsigned short* __restrict__ h1b, const unsigned short* __restrict__ W2T,
        const float* __restrict__ al2, const float* __restrict__ ar2,
        float* __restrict__ feat2, float* __restrict__ el2, float* __restrict__ er2) {
    int wave = threadIdx.x >> 6, lane = threadIdx.x & 63;
    int l16 = lane & 15, quad = lane >> 4;
    int row0 = (blockIdx.x * 4 + wave) * 16;
    if (row0 >= N_NODES) return;
    floatx4 acc = (floatx4){0.f, 0.f, 0.f, 0.f};
    const unsigned short* arow = h1b + (size_t)(row0 + l16) * 256 + quad * 8;
    const unsigned short* brow = W2T + (size_t)l16 * 256 + quad * 8;
#pragma unroll
    for (int k0 = 0; k0 < 256; k0 += 32) {
        short8 a = *(const short8*)(arow + k0);
        short8 b = *(const short8*)(brow + k0);
        acc = __builtin_amdgcn_mfma_f32_16x16x32_bf16(a, b, acc, 0, 0, 0);
    }
    float a2 = al2[l16], r2 = ar2[l16];
#pragma unroll
    for (int r = 0; r < 4; ++r) {
        int row = row0 + quad * 4 + r;
        float v = acc[r];
        feat2[row * 16 + l16] = v;
        float pl = v * a2, pr = v * r2;
#pragma unroll
        for (int off = 1; off < 16; off <<= 1) {
            pl += __shfl_xor(pl, off);
            pr += __shfl_xor(pr, off);
        }
        if (l16 == 0) {
            el2[row] = pl;
            er2[row] = pr;
        }
    }
}

// ---------------- layer-2 aggregation + log_softmax, 2x unroll ----------------
__global__ void agg2_kernel(const float* __restrict__ feat2, const float* __restrict__ el2,
                            const float* __restrict__ er2, const int* __restrict__ row_ptr,
                            const int* __restrict__ csr_src, const float* __restrict__ b2,
                            float* __restrict__ out) {
    int wave = threadIdx.x >> 6, lane = threadIdx.x & 63;
    int n = blockIdx.x * 4 + wave;
    if (n >= N_NODES) return;
    int start = row_ptr[n], end = row_ptr[n + 1];
    float ern = er2[n];
    int eo = lane >> 4, c = lane & 15;
    float acc = 0.f, denom = 0.f;
    int i = start + eo;
    for (; i + 4 < end; i += 8) {
        int s0 = csr_src[i], s1 = csr_src[i + 4];
        float ex0 = __expf(leaky(el2[s0] + ern));
        float ex1 = __expf(leaky(el2[s1] + ern));
        float f0 = feat2[s0 * 16 + c], f1 = feat2[s1 * 16 + c];
        denom += ex0 + ex1;
        acc = fmaf(f0, ex0, acc);
        acc = fmaf(f1, ex1, acc);
    }
    if (i < end) {
        int s = csr_src[i];
        float ex = __expf(leaky(el2[s] + ern));
        denom += ex;
        acc = fmaf(feat2[s * 16 + c], ex, acc);
    }
    acc += __shfl_xor(acc, 16);
    acc += __shfl_xor(acc, 32);
    denom += __shfl_xor(denom, 16);
    denom += __shfl_xor(denom, 32);
    float v = ((end > start) ? acc / denom : 0.f) + b2[c];
    float mx = v;
#pragma unroll
    for (int off = 1; off < 16; off <<= 1) mx = fmaxf(mx, __shfl_xor(mx, off));
    float ex2 = __expf(v - mx);
    float s2 = ex2;
#pragma unroll
    for (int off = 1; off < 16; off <<= 1) s2 += __shfl_xor(s2, off);
    float res = v - mx - logf(s2);
    if (lane < 16) out[n * 16 + lane] = res;
}

// ---------------- launch ----------------
extern "C" void kernel_launch(void* const* d_in, const int* in_sizes, int n_in,
                              void* d_out, int out_size, void* d_ws, size_t ws_size,
                              hipStream_t stream) {
    const float* x   = (const float*)d_in[0];
    const int*   src = (const int*)d_in[1];
    const int*   dst = (const int*)d_in[2];
    const float* W1  = (const float*)d_in[3];
    const float* al1 = (const float*)d_in[4];
    const float* ar1 = (const float*)d_in[5];
    const float* b1  = (const float*)d_in[6];
    const float* W2  = (const float*)d_in[7];
    const float* al2 = (const float*)d_in[8];
    const float* ar2 = (const float*)d_in[9];
    const float* b2  = (const float*)d_in[10];
    float* out = (float*)d_out;

    char* ws = (char*)d_ws;
    size_t off = 0;
    auto alloc = [&](size_t bytes) -> void* {
        void* p = ws + off;
        off += (bytes + 255) & ~(size_t)255;
        return p;
    };
    unsigned short* W1E   = (unsigned short*)alloc((size_t)272 * 256 * 2);
    unsigned short* W2T   = (unsigned short*)alloc((size_t)16 * 256 * 2);
    unsigned char*  feat1 = (unsigned char*)alloc((size_t)N_NODES * 256);
    unsigned short* h1b   = (unsigned short*)alloc((size_t)N_NODES * 256 * 2);
    float* feat2   = (float*)alloc((size_t)N_NODES * 16 * 4);
    float* el1     = (float*)alloc((size_t)N_NODES * 4 * 4);
    float* er1     = (float*)alloc((size_t)N_NODES * 4 * 4);
    float* el2     = (float*)alloc((size_t)N_NODES * 4);
    float* er2     = (float*)alloc((size_t)N_NODES * 4);
    int*   bhist   = (int*)alloc((size_t)NSCAN * 4);
    int*   partial = (int*)alloc((size_t)NSCAN * 4);
    int*   bsum    = (int*)alloc((size_t)256 * 4);
    int*   row_ptr = (int*)alloc((size_t)NP1 * 4);
    int*   ebuf    = (int*)alloc((size_t)N_EDGES * 4);
    int*   csr_src = (int*)alloc((size_t)N_EDGES * 4);

    dim3 b256(256);
    p1_kernel<<<NBLK + 21, b256, 0, stream>>>(dst, bhist, W1, W2, al1, ar1, W1E, W2T);
    scanA_kernel<<<NSCB, b256, 0, stream>>>(bhist, partial, bsum);
    p2_kernel<<<NBLK, b256, 0, stream>>>(src, dst, partial, bsum, ebuf);
    p3_kernel<<<NBUCK, b256, 0, stream>>>(partial, bsum, ebuf, row_ptr, csr_src);

    gemm1_mfma_kernel<<<(N_NODES + 127) / 128, b256, 0, stream>>>(x, W1E, feat1, el1, er1);
    agg1_kernel<<<(N_NODES + 3) / 4, b256, 0, stream>>>(feat1, el1, er1, row_ptr, csr_src, b1, h1b);

    gemm2_mfma_kernel<<<(N_NODES + 63) / 64, b256, 0, stream>>>(h1b, W2T, al2, ar2, feat2, el2, er2);
    agg2_kernel<<<(N_NODES + 3) / 4, b256, 0, stream>>>(feat2, el2, er2, row_ptr, csr_src, b2, out);
}

// Round 9
// 247.606 us; speedup vs baseline: 1.3489x; 1.0221x over previous
//
#include <hip/hip_runtime.h>
#include <hip/hip_bf16.h>

#define N_NODES 50000
#define NP1     50001
#define N_EDGES 800000
#define NFEAT   256
#define NHID    64
#define HEADS   4
#define NCLASS  16
#define NEG_SLOPE 0.2f

#define NBLK  782                 // edge blocks (1024 edges each)
#define NBUCK 196                 // buckets of 256 nodes (dst >> 8)
#define NSCAN (NBUCK * NBLK)      // 153272
#define NSCB  150                 // ceil(NSCAN / 1024)
#define MAXB  5120                // max edges per bucket (avg 4096, sigma 64)

typedef __attribute__((ext_vector_type(8))) short short8;
typedef __attribute__((ext_vector_type(4))) float floatx4;
typedef __attribute__((ext_vector_type(2))) float floatx2;

__device__ __forceinline__ float blo(unsigned int u) { return __uint_as_float(u << 16); }
__device__ __forceinline__ float bhi(unsigned int u) { return __uint_as_float(u & 0xffff0000u); }
__device__ __forceinline__ float b2f(unsigned short u) {
    return __uint_as_float(((unsigned int)u) << 16);
}
__device__ __forceinline__ unsigned short f2b(float f) {
    unsigned int x = __float_as_uint(f);
    unsigned int r = x + 0x7fffu + ((x >> 16) & 1u);
    return (unsigned short)(r >> 16);
}
__device__ __forceinline__ unsigned int pack2(float a, float b) {
    return (unsigned int)f2b(a) | ((unsigned int)f2b(b) << 16);
}
__device__ __forceinline__ float leaky(float x) { return fmaxf(x, NEG_SLOPE * x); }

__device__ __forceinline__ void fp8acc(uint4 u, float ex, float* acc) {
    floatx2 p;
    p = __builtin_amdgcn_cvt_pk_f32_fp8(u.x, 0); acc[0]  = fmaf(p[0], ex, acc[0]);  acc[1]  = fmaf(p[1], ex, acc[1]);
    p = __builtin_amdgcn_cvt_pk_f32_fp8(u.x, 1); acc[2]  = fmaf(p[0], ex, acc[2]);  acc[3]  = fmaf(p[1], ex, acc[3]);
    p = __builtin_amdgcn_cvt_pk_f32_fp8(u.y, 0); acc[4]  = fmaf(p[0], ex, acc[4]);  acc[5]  = fmaf(p[1], ex, acc[5]);
    p = __builtin_amdgcn_cvt_pk_f32_fp8(u.y, 1); acc[6]  = fmaf(p[0], ex, acc[6]);  acc[7]  = fmaf(p[1], ex, acc[7]);
    p = __builtin_amdgcn_cvt_pk_f32_fp8(u.z, 0); acc[8]  = fmaf(p[0], ex, acc[8]);  acc[9]  = fmaf(p[1], ex, acc[9]);
    p = __builtin_amdgcn_cvt_pk_f32_fp8(u.z, 1); acc[10] = fmaf(p[0], ex, acc[10]); acc[11] = fmaf(p[1], ex, acc[11]);
    p = __builtin_amdgcn_cvt_pk_f32_fp8(u.w, 0); acc[12] = fmaf(p[0], ex, acc[12]); acc[13] = fmaf(p[1], ex, acc[13]);
    p = __builtin_amdgcn_cvt_pk_f32_fp8(u.w, 1); acc[14] = fmaf(p[0], ex, acc[14]); acc[15] = fmaf(p[1], ex, acc[15]);
}

// ---------------- P1: per-block bucket histogram + fused weight prep ----------------
__global__ __launch_bounds__(256) void p1_kernel(
        const int* __restrict__ dst, int* __restrict__ bhist,
        const float* __restrict__ W1, const float* __restrict__ W2,
        const float* __restrict__ al1, const float* __restrict__ ar1,
        unsigned short* __restrict__ W1E, unsigned short* __restrict__ W2T) {
    __shared__ float tile[64][65];
    __shared__ int hist[NBUCK];
    int b = blockIdx.x, t = threadIdx.x;
    if (b < NBLK) {
        if (t < NBUCK) hist[t] = 0;
        __syncthreads();
        int e = (b * 256 + t) * 4;
        if (e < N_EDGES) {
            int4 d = *(const int4*)&dst[e];
            atomicAdd(&hist[d.x >> 8], 1);
            atomicAdd(&hist[d.y >> 8], 1);
            atomicAdd(&hist[d.z >> 8], 1);
            atomicAdd(&hist[d.w >> 8], 1);
        }
        __syncthreads();
        if (t < NBUCK) bhist[t * NBLK + b] = hist[t];
        return;
    }
    int pb = b - NBLK;
    if (pb < 16) {
        int tk = (pb & 3) * 64, tn = (pb >> 2) * 64;
        int tx = t & 63, ty = t >> 6;
#pragma unroll
        for (int r = 0; r < 16; ++r) {
            int row = ty * 16 + r;
            tile[row][tx] = W1[(tk + row) * 256 + tn + tx];
        }
        __syncthreads();
#pragma unroll
        for (int r = 0; r < 16; ++r) {
            int row = ty * 16 + r;
            W1E[(tn + row) * 256 + tk + tx] = f2b(tile[tx][row]);
        }
    } else if (pb < 20) {
        int h = pb - 16;
        int w = t >> 6, lane = t & 63;
        float alv = al1[h * 64 + lane];
        float arv = ar1[h * 64 + lane];
        for (int k = w; k < 256; k += 4) {
            float wv = W1[k * 256 + h * 64 + lane];
            float sl = wv * alv, sr = wv * arv;
#pragma unroll
            for (int off = 1; off < 64; off <<= 1) {
                sl += __shfl_xor(sl, off);
                sr += __shfl_xor(sr, off);
            }
            if (lane == 0) {
                W1E[(256 + h) * 256 + k] = f2b(sl);
                W1E[(260 + h) * 256 + k] = f2b(sr);
            }
        }
    } else {
        int n = t >> 4, k0 = (t & 15) * 16;
#pragma unroll
        for (int j = 0; j < 16; ++j)
            W2T[n * 256 + k0 + j] = f2b(W2[(k0 + j) * 16 + n]);
#pragma unroll
        for (int j = 0; j < 8; ++j)
            W1E[264 * 256 + j * 256 + t] = 0;
    }
}

// ---------------- scanA: per-chunk (1024) exclusive scan of bhist ----------------
__global__ __launch_bounds__(256) void scanA_kernel(const int* __restrict__ bhist,
                                                    int* __restrict__ partial,
                                                    int* __restrict__ bsum) {
    __shared__ int wsum[4];
    int t = threadIdx.x;
    int base = blockIdx.x * 1024 + t * 4;
    int v0 = (base + 0 < NSCAN) ? bhist[base + 0] : 0;
    int v1 = (base + 1 < NSCAN) ? bhist[base + 1] : 0;
    int v2 = (base + 2 < NSCAN) ? bhist[base + 2] : 0;
    int v3 = (base + 3 < NSCAN) ? bhist[base + 3] : 0;
    int s = v0 + v1 + v2 + v3;
    int lane = t & 63, w = t >> 6;
    int incl = s;
#pragma unroll
    for (int off = 1; off < 64; off <<= 1) {
        int x = __shfl_up(incl, off);
        if (lane >= off) incl += x;
    }
    if (lane == 63) wsum[w] = incl;
    __syncthreads();
    int woff = 0;
    for (int k = 0; k < w; ++k) woff += wsum[k];
    int excl = woff + incl - s;
    if (base + 0 < NSCAN) partial[base + 0] = excl;
    if (base + 1 < NSCAN) partial[base + 1] = excl + v0;
    if (base + 2 < NSCAN) partial[base + 2] = excl + v0 + v1;
    if (base + 3 < NSCAN) partial[base + 3] = excl + v0 + v1 + v2;
    if (t == 255) bsum[blockIdx.x] = woff + incl;
}

// ---------------- P2: LDS bucket presort, then contiguous-run writes to ebuf ----------------
__global__ __launch_bounds__(256) void p2_kernel(const int* __restrict__ src,
                                                 const int* __restrict__ dst,
                                                 const int* __restrict__ partial,
                                                 const int* __restrict__ bsum,
                                                 unsigned int* __restrict__ ebuf) {
    __shared__ int wsum[4];
    __shared__ int sb[256];
    __shared__ int bs[NBUCK];
    __shared__ int lcnt[256];
    __shared__ int lofs[256];
    __shared__ int lfill[256];
    __shared__ unsigned int sorted[1024];
    int b = blockIdx.x, t = threadIdx.x;
    int lane = t & 63, w = t >> 6;
    // inline exclusive scan of bsum
    {
        int v = (t < NSCB) ? bsum[t] : 0;
        int incl = v;
#pragma unroll
        for (int off = 1; off < 64; off <<= 1) {
            int x = __shfl_up(incl, off);
            if (lane >= off) incl += x;
        }
        if (lane == 63) wsum[w] = incl;
        __syncthreads();
        int woff = 0;
        for (int k = 0; k < w; ++k) woff += wsum[k];
        sb[t] = woff + incl - v;
    }
    lcnt[t] = 0;
    __syncthreads();
    if (t < NBUCK) {
        int idx = t * NBLK + b;
        bs[t] = partial[idx] + sb[idx >> 10];
    }
    int e = (b * 256 + t) * 4;
    int4 d, s;
    bool valid = e < N_EDGES;
    if (valid) {
        d = *(const int4*)&dst[e];
        s = *(const int4*)&src[e];
        atomicAdd(&lcnt[d.x >> 8], 1);
        atomicAdd(&lcnt[d.y >> 8], 1);
        atomicAdd(&lcnt[d.z >> 8], 1);
        atomicAdd(&lcnt[d.w >> 8], 1);
    }
    __syncthreads();
    // scan lcnt (256 entries) -> block-local exclusive offsets
    {
        int v = lcnt[t];
        int incl = v;
#pragma unroll
        for (int off = 1; off < 64; off <<= 1) {
            int x = __shfl_up(incl, off);
            if (lane >= off) incl += x;
        }
        if (lane == 63) wsum[w] = incl;
        __syncthreads();
        int woff = 0;
        for (int k = 0; k < w; ++k) woff += wsum[k];
        int excl = woff + incl - v;
        lofs[t] = excl;
        lfill[t] = excl;
    }
    __syncthreads();
    if (valid) {
        int p0 = atomicAdd(&lfill[d.x >> 8], 1);
        sorted[p0] = ((unsigned int)s.x << 16) | (unsigned int)d.x;
        int p1 = atomicAdd(&lfill[d.y >> 8], 1);
        sorted[p1] = ((unsigned int)s.y << 16) | (unsigned int)d.y;
        int p2 = atomicAdd(&lfill[d.z >> 8], 1);
        sorted[p2] = ((unsigned int)s.z << 16) | (unsigned int)d.z;
        int p3 = atomicAdd(&lfill[d.w >> 8], 1);
        sorted[p3] = ((unsigned int)s.w << 16) | (unsigned int)d.w;
    }
    __syncthreads();
    int ve = min(1024, N_EDGES - b * 1024);
    for (int i = t; i < ve; i += 256) {
        unsigned int p = sorted[i];
        int k = (p & 0xFFFFu) >> 8;
        ebuf[bs[k] + (i - lofs[k])] = p;
    }
}

// ---------------- P3: per-bucket LDS node presort -> coalesced csr_src + row_ptr ----------------
__global__ __launch_bounds__(256) void p3_kernel(const int* __restrict__ partial,
                                                 const int* __restrict__ bsum,
                                                 const unsigned int* __restrict__ ebuf,
                                                 int* __restrict__ row_ptr,
                                                 int* __restrict__ csr_src) {
    __shared__ int wsum[4];
    __shared__ int sb[256];
    __shared__ int lcnt[256];
    __shared__ int lfill[256];
    __shared__ int sorted[MAXB];
    int b = blockIdx.x, t = threadIdx.x;
    int lane = t & 63, w = t >> 6;
    {
        int v = (t < NSCB) ? bsum[t] : 0;
        int incl = v;
#pragma unroll
        for (int off = 1; off < 64; off <<= 1) {
            int x = __shfl_up(incl, off);
            if (lane >= off) incl += x;
        }
        if (lane == 63) wsum[w] = incl;
        __syncthreads();
        int woff = 0;
        for (int k = 0; k < w; ++k) woff += wsum[k];
        sb[t] = woff + incl - v;
    }
    __syncthreads();
    int i0 = b * NBLK;
    int base = partial[i0] + sb[i0 >> 10];
    int endb;
    if (b == NBUCK - 1) endb = N_EDGES;
    else {
        int i1 = (b + 1) * NBLK;
        endb = partial[i1] + sb[i1 >> 10];
    }
    lcnt[t] = 0;
    __syncthreads();
    for (int i = base + t; i < endb; i += 256)
        atomicAdd(&lcnt[ebuf[i] & 255u], 1);
    __syncthreads();
    {
        int v = lcnt[t];
        int incl = v;
#pragma unroll
        for (int off = 1; off < 64; off <<= 1) {
            int x = __shfl_up(incl, off);
            if (lane >= off) incl += x;
        }
        if (lane == 63) wsum[w] = incl;
        __syncthreads();
        int woff = 0;
        for (int k = 0; k < w; ++k) woff += wsum[k];
        int excl = woff + incl - v;
        lfill[t] = excl;
        int node = b * 256 + t;
        if (node < NP1) row_ptr[node] = base + excl;
    }
    __syncthreads();
    for (int i = base + t; i < endb; i += 256) {
        unsigned int p = ebuf[i];
        int pos = atomicAdd(&lfill[p & 255u], 1);
        sorted[pos] = (int)(p >> 16);
    }
    __syncthreads();
    int M = endb - base;
    for (int i = t; i < M; i += 256)
        csr_src[base + i] = sorted[i];
}

// ---------------- GEMM1 (bf16 MFMA): [feat1(fp8) | el | er] = x @ [W1 | Wel | Wer] ----------------
__global__ __launch_bounds__(256, 2) void gemm1_mfma_kernel(
        const float* __restrict__ X, const unsigned short* __restrict__ BT,
        unsigned char* __restrict__ C, float* __restrict__ el, float* __restrict__ er) {
    __shared__ __align__(16) unsigned short As[128 * 40];
    __shared__ __align__(16) unsigned short Bs[272 * 40];
    int t = threadIdx.x;
    int m0 = blockIdx.x * 128;
    int lane = t & 63, wm = t >> 6;
    int quad = lane >> 4, l16 = lane & 15;

    floatx4 acc[2][17];
#pragma unroll
    for (int i = 0; i < 2; ++i)
#pragma unroll
        for (int j = 0; j < 17; ++j) acc[i][j] = (floatx4){0.f, 0.f, 0.f, 0.f};

    int arow = t >> 1, ak = (t & 1) * 16;
    int grow = m0 + arow;
    const float* xrow = X + (size_t)grow * 256 + ak;

    for (int k0 = 0; k0 < 256; k0 += 32) {
        float4 v0 = make_float4(0.f, 0.f, 0.f, 0.f), v1 = v0, v2 = v0, v3 = v0;
        if (grow < N_NODES) {
            v0 = *(const float4*)(xrow + k0 + 0);
            v1 = *(const float4*)(xrow + k0 + 4);
            v2 = *(const float4*)(xrow + k0 + 8);
            v3 = *(const float4*)(xrow + k0 + 12);
        }
        uint4 p0, p1;
        p0.x = pack2(v0.x, v0.y); p0.y = pack2(v0.z, v0.w);
        p0.z = pack2(v1.x, v1.y); p0.w = pack2(v1.z, v1.w);
        p1.x = pack2(v2.x, v2.y); p1.y = pack2(v2.z, v2.w);
        p1.z = pack2(v3.x, v3.y); p1.w = pack2(v3.z, v3.w);
        *(uint4*)&As[arow * 40 + ak] = p0;
        *(uint4*)&As[arow * 40 + ak + 8] = p1;
#pragma unroll
        for (int i = 0; i < 5; ++i) {
            int ch = t + i * 256;
            if (ch < 1088) {
                int row = ch >> 2, off = (ch & 3) * 8;
                *(uint4*)&Bs[row * 40 + off] = *(const uint4*)(BT + row * 256 + k0 + off);
            }
        }
        __syncthreads();

        short8 a0 = *(const short8*)&As[(wm * 32 + l16) * 40 + quad * 8];
        short8 a1 = *(const short8*)&As[(wm * 32 + 16 + l16) * 40 + quad * 8];
#pragma unroll
        for (int nf = 0; nf < 17; ++nf) {
            short8 bb = *(const short8*)&Bs[(nf * 16 + l16) * 40 + quad * 8];
            acc[0][nf] = __builtin_amdgcn_mfma_f32_16x16x32_bf16(a0, bb, acc[0][nf], 0, 0, 0);
            acc[1][nf] = __builtin_amdgcn_mfma_f32_16x16x32_bf16(a1, bb, acc[1][nf], 0, 0, 0);
        }
        __syncthreads();
    }

#pragma unroll
    for (int mf = 0; mf < 2; ++mf) {
#pragma unroll
        for (int r = 0; r < 4; ++r) {
            int row = m0 + wm * 32 + mf * 16 + quad * 4 + r;
            if (row < N_NODES && l16 < 8) {
                float v = acc[mf][16][r];
                if (l16 < 4) el[row * 4 + l16] = v;
                else er[row * 4 + (l16 - 4)] = v;
            }
        }
    }

    unsigned short* scr = Bs + wm * 1536;
    int half = lane >> 5, l32 = lane & 31;
    int rrow = l32 >> 1, coff = (l32 & 1) * 8;
#pragma unroll
    for (int mf = 0; mf < 2; ++mf) {
#pragma unroll
        for (int p = 0; p < 8; ++p) {
            unsigned short* base = scr + (p & 1) * 768;
#pragma unroll
            for (int fr = 0; fr < 2; ++fr) {
                int nf = 2 * p + fr;
                unsigned short* fb = base + fr * 384;
#pragma unroll
                for (int r = 0; r < 4; ++r)
                    fb[(quad * 4 + r) * 24 + l16] = f2b(acc[mf][nf][r]);
            }
            uint4 val = *(const uint4*)(base + half * 384 + rrow * 24 + coff);
            int row = m0 + wm * 32 + mf * 16 + rrow;
            int nf = 2 * p + half;
            if (row < N_NODES) {
                float f0 = blo(val.x), f1 = bhi(val.x), f2 = blo(val.y), f3 = bhi(val.y);
                float f4 = blo(val.z), f5 = bhi(val.z), f6 = blo(val.w), f7 = bhi(val.w);
                int lo = __builtin_amdgcn_cvt_pk_fp8_f32(f0, f1, 0, 0);
                lo = __builtin_amdgcn_cvt_pk_fp8_f32(f2, f3, lo, 1);
                int hi = __builtin_amdgcn_cvt_pk_fp8_f32(f4, f5, 0, 0);
                hi = __builtin_amdgcn_cvt_pk_fp8_f32(f6, f7, hi, 1);
                uint2 o;
                o.x = (unsigned int)lo;
                o.y = (unsigned int)hi;
                *(uint2*)&C[(size_t)row * 256 + nf * 16 + coff] = o;
            }
        }
    }
}

// ---------------- layer-1 aggregation: fp8 gather, quarter-wave per edge, 2x unroll ----------------
__global__ void agg1_kernel(const unsigned char* __restrict__ feat1,
                            const float* __restrict__ el, const float* __restrict__ er,
                            const int* __restrict__ row_ptr, const int* __restrict__ csr_src,
                            const float* __restrict__ b1, unsigned short* __restrict__ h1b) {
    int wave = threadIdx.x >> 6, lane = threadIdx.x & 63;
    int n = blockIdx.x * 4 + wave;
    if (n >= N_NODES) return;
    int q = lane >> 4, l16 = lane & 15;
    int h = l16 >> 2;
    float er_h = er[n * 4 + h];
    int start = row_ptr[n], end = row_ptr[n + 1];

    float acc[16];
#pragma unroll
    for (int j = 0; j < 16; ++j) acc[j] = 0.f;
    float denom = 0.f;

    int i = start + q;
    for (; i + 4 < end; i += 8) {
        int s0 = csr_src[i];
        int s1 = csr_src[i + 4];
        float ex0 = __expf(leaky(el[s0 * 4 + h] + er_h));
        float ex1 = __expf(leaky(el[s1 * 4 + h] + er_h));
        uint4 a = *(const uint4*)(feat1 + (size_t)s0 * 256 + l16 * 16);
        uint4 b = *(const uint4*)(feat1 + (size_t)s1 * 256 + l16 * 16);
        denom += ex0 + ex1;
        fp8acc(a, ex0, acc);
        fp8acc(b, ex1, acc);
    }
    if (i < end) {
        int s = csr_src[i];
        float ex = __expf(leaky(el[s * 4 + h] + er_h));
        uint4 u = *(const uint4*)(feat1 + (size_t)s * 256 + l16 * 16);
        denom += ex;
        fp8acc(u, ex, acc);
    }
#pragma unroll
    for (int j = 0; j < 16; ++j) {
        acc[j] += __shfl_xor(acc[j], 16);
        acc[j] += __shfl_xor(acc[j], 32);
    }
    denom += __shfl_xor(denom, 16);
    denom += __shfl_xor(denom, 32);

    if (q == 0) {
        float inv = (end > start) ? 1.f / denom : 0.f;
        float o[16];
#pragma unroll
        for (int j = 0; j < 16; j += 4) {
            float4 b4 = *(const float4*)&b1[l16 * 16 + j];
            o[j + 0] = fmaf(acc[j + 0], inv, b4.x);
            o[j + 1] = fmaf(acc[j + 1], inv, b4.y);
            o[j + 2] = fmaf(acc[j + 2], inv, b4.z);
            o[j + 3] = fmaf(acc[j + 3], inv, b4.w);
        }
#pragma unroll
        for (int j = 0; j < 16; ++j) o[j] = o[j] > 0.f ? o[j] : __expf(o[j]) - 1.f;
        uint4 pa, pb;
        pa.x = pack2(o[0], o[1]);   pa.y = pack2(o[2], o[3]);
        pa.z = pack2(o[4], o[5]);   pa.w = pack2(o[6], o[7]);
        pb.x = pack2(o[8], o[9]);   pb.y = pack2(o[10], o[11]);
        pb.z = pack2(o[12], o[13]); pb.w = pack2(o[14], o[15]);
        uint4* dstp = (uint4*)(h1b + (size_t)n * 256 + l16 * 16);
        dstp[0] = pa;
        dstp[1] = pb;
    }
}

// ---------------- GEMM2 (bf16 MFMA, no LDS) + fused el2/er2, bf16 feat2 out ----------------
__global__ __launch_bounds__(256) void gemm2_mfma_kernel(
        const unsigned short* __restrict__ h1b, const unsigned short* __restrict__ W2T,
        const float* __restrict__ al2, const float* __restrict__ ar2,
        unsigned short* __restrict__ feat2b, float* __restrict__ el2, float* __restrict__ er2) {
    int wave = threadIdx.x >> 6, lane = threadIdx.x & 63;
    int l16 = lane & 15, quad = lane >> 4;
    int row0 = (blockIdx.x * 4 + wave) * 16;
    if (row0 >= N_NODES) return;
    floatx4 acc = (floatx4){0.f, 0.f, 0.f, 0.f};
    const unsigned short* arow = h1b + (size_t)(row0 + l16) * 256 + quad * 8;
    const unsigned short* brow = W2T + (size_t)l16 * 256 + quad * 8;
#pragma unroll
    for (int k0 = 0; k0 < 256; k0 += 32) {
        short8 a = *(const short8*)(arow + k0);
        short8 b = *(const short8*)(brow + k0);
        acc = __builtin_amdgcn_mfma_f32_16x16x32_bf16(a, b, acc, 0, 0, 0);
    }
    float a2 = al2[l16], r2 = ar2[l16];
#pragma unroll
    for (int r = 0; r < 4; ++r) {
        int row = row0 + quad * 4 + r;
        float v = acc[r];
        feat2b[row * 16 + l16] = f2b(v);
        float pl = v * a2, pr = v * r2;
#pragma unroll
        for (int off = 1; off < 16; off <<= 1) {
            pl += __shfl_xor(pl, off);
            pr += __shfl_xor(pr, off);
        }
        if (l16 == 0) {
            el2[row] = pl;
            er2[row] = pr;
        }
    }
}

// ---------------- layer-2 aggregation + log_softmax, bf16 feat2, 2x unroll ----------------
__global__ void agg2_kernel(const unsigned short* __restrict__ feat2b,
                            const float* __restrict__ el2, const float* __restrict__ er2,
                            const int* __restrict__ row_ptr, const int* __restrict__ csr_src,
                            const float* __restrict__ b2, float* __restrict__ out) {
    int wave = threadIdx.x >> 6, lane = threadIdx.x & 63;
    int n = blockIdx.x * 4 + wave;
    if (n >= N_NODES) return;
    int start = row_ptr[n], end = row_ptr[n + 1];
    float ern = er2[n];
    int eo = lane >> 4, c = lane & 15;
    float acc = 0.f, denom = 0.f;
    int i = start + eo;
    for (; i + 4 < end; i += 8) {
        int s0 = csr_src[i], s1 = csr_src[i + 4];
        float ex0 = __expf(leaky(el2[s0] + ern));
        float ex1 = __expf(leaky(el2[s1] + ern));
        float f0 = b2f(feat2b[s0 * 16 + c]), f1 = b2f(feat2b[s1 * 16 + c]);
        denom += ex0 + ex1;
        acc = fmaf(f0, ex0, acc);
        acc = fmaf(f1, ex1, acc);
    }
    if (i < end) {
        int s = csr_src[i];
        float ex = __expf(leaky(el2[s] + ern));
        denom += ex;
        acc = fmaf(b2f(feat2b[s * 16 + c]), ex, acc);
    }
    acc += __shfl_xor(acc, 16);
    acc += __shfl_xor(acc, 32);
    denom += __shfl_xor(denom, 16);
    denom += __shfl_xor(denom, 32);
    float v = ((end > start) ? acc / denom : 0.f) + b2[c];
    float mx = v;
#pragma unroll
    for (int off = 1; off < 16; off <<= 1) mx = fmaxf(mx, __shfl_xor(mx, off));
    float ex2 = __expf(v - mx);
    float s2 = ex2;
#pragma unroll
    for (int off = 1; off < 16; off <<= 1) s2 += __shfl_xor(s2, off);
    float res = v - mx - logf(s2);
    if (lane < 16) out[n * 16 + lane] = res;
}

// ---------------- launch ----------------
extern "C" void kernel_launch(void* const* d_in, const int* in_sizes, int n_in,
                              void* d_out, int out_size, void* d_ws, size_t ws_size,
                              hipStream_t stream) {
    const float* x   = (const float*)d_in[0];
    const int*   src = (const int*)d_in[1];
    const int*   dst = (const int*)d_in[2];
    const float* W1  = (const float*)d_in[3];
    const float* al1 = (const float*)d_in[4];
    const float* ar1 = (const float*)d_in[5];
    const float* b1  = (const float*)d_in[6];
    const float* W2  = (const float*)d_in[7];
    const float* al2 = (const float*)d_in[8];
    const float* ar2 = (const float*)d_in[9];
    const float* b2  = (const float*)d_in[10];
    float* out = (float*)d_out;

    char* ws = (char*)d_ws;
    size_t off = 0;
    auto alloc = [&](size_t bytes) -> void* {
        void* p = ws + off;
        off += (bytes + 255) & ~(size_t)255;
        return p;
    };
    unsigned short* W1E    = (unsigned short*)alloc((size_t)272 * 256 * 2);
    unsigned short* W2T    = (unsigned short*)alloc((size_t)16 * 256 * 2);
    unsigned char*  feat1  = (unsigned char*)alloc((size_t)N_NODES * 256);
    unsigned short* h1b    = (unsigned short*)alloc((size_t)N_NODES * 256 * 2);
    unsigned short* feat2b = (unsigned short*)alloc((size_t)N_NODES * 16 * 2);
    float* el1     = (float*)alloc((size_t)N_NODES * 4 * 4);
    float* er1     = (float*)alloc((size_t)N_NODES * 4 * 4);
    float* el2     = (float*)alloc((size_t)N_NODES * 4);
    float* er2     = (float*)alloc((size_t)N_NODES * 4);
    int*   bhist   = (int*)alloc((size_t)NSCAN * 4);
    int*   partial = (int*)alloc((size_t)NSCAN * 4);
    int*   bsum    = (int*)alloc((size_t)256 * 4);
    int*   row_ptr = (int*)alloc((size_t)NP1 * 4);
    unsigned int* ebuf = (unsigned int*)alloc((size_t)N_EDGES * 4);
    int*   csr_src = (int*)alloc((size_t)N_EDGES * 4);

    dim3 b256(256);
    p1_kernel<<<NBLK + 21, b256, 0, stream>>>(dst, bhist, W1, W2, al1, ar1, W1E, W2T);
    scanA_kernel<<<NSCB, b256, 0, stream>>>(bhist, partial, bsum);
    p2_kernel<<<NBLK, b256, 0, stream>>>(src, dst, partial, bsum, ebuf);
    p3_kernel<<<NBUCK, b256, 0, stream>>>(partial, bsum, ebuf, row_ptr, csr_src);

    gemm1_mfma_kernel<<<(N_NODES + 127) / 128, b256, 0, stream>>>(x, W1E, feat1, el1, er1);
    agg1_kernel<<<(N_NODES + 3) / 4, b256, 0, stream>>>(feat1, el1, er1, row_ptr, csr_src, b1, h1b);

    gemm2_mfma_kernel<<<(N_NODES + 63) / 64, b256, 0, stream>>>(h1b, W2T, al2, ar2, feat2b, el2, er2);
    agg2_kernel<<<(N_NODES + 3) / 4, b256, 0, stream>>>(feat2b, el2, er2, row_ptr, csr_src, b2, out);
}

// Round 10
// 245.071 us; speedup vs baseline: 1.3629x; 1.0103x over previous
//
#include <hip/hip_runtime.h>
#include <hip/hip_bf16.h>

#define N_NODES 50000
#define NP1     50001
#define N_EDGES 800000
#define NFEAT   256
#define NHID    64
#define HEADS   4
#define NCLASS  16
#define NEG_SLOPE 0.2f

#define NBLK  782                 // edge blocks (1024 edges each)
#define NBUCK 196                 // buckets of 256 nodes (dst >> 8)
#define NSCAN (NBUCK * NBLK)      // 153272
#define NSCB  150                 // ceil(NSCAN / 1024)
#define MAXB  5120                // max edges per bucket (avg 4096)
#define NGB   391                 // gemm1 blocks: (N_NODES+127)/128

typedef __attribute__((ext_vector_type(8))) short short8;
typedef __attribute__((ext_vector_type(4))) float floatx4;
typedef __attribute__((ext_vector_type(2))) float floatx2;

__device__ __forceinline__ float blo(unsigned int u) { return __uint_as_float(u << 16); }
__device__ __forceinline__ float bhi(unsigned int u) { return __uint_as_float(u & 0xffff0000u); }
__device__ __forceinline__ float b2f(unsigned short u) {
    return __uint_as_float(((unsigned int)u) << 16);
}
__device__ __forceinline__ unsigned short f2b(float f) {
    unsigned int x = __float_as_uint(f);
    unsigned int r = x + 0x7fffu + ((x >> 16) & 1u);
    return (unsigned short)(r >> 16);
}
__device__ __forceinline__ unsigned int pack2(float a, float b) {
    return (unsigned int)f2b(a) | ((unsigned int)f2b(b) << 16);
}
__device__ __forceinline__ float leaky(float x) { return fmaxf(x, NEG_SLOPE * x); }

// fp8 unpack + packed-fp32 accumulate: 8 cvt_pk + 8 v_pk_fma_f32 per 16 features
__device__ __forceinline__ void fp8acc2(uint4 u, floatx2 exv, floatx2* acc) {
    acc[0] = __builtin_elementwise_fma(__builtin_amdgcn_cvt_pk_f32_fp8(u.x, 0), exv, acc[0]);
    acc[1] = __builtin_elementwise_fma(__builtin_amdgcn_cvt_pk_f32_fp8(u.x, 1), exv, acc[1]);
    acc[2] = __builtin_elementwise_fma(__builtin_amdgcn_cvt_pk_f32_fp8(u.y, 0), exv, acc[2]);
    acc[3] = __builtin_elementwise_fma(__builtin_amdgcn_cvt_pk_f32_fp8(u.y, 1), exv, acc[3]);
    acc[4] = __builtin_elementwise_fma(__builtin_amdgcn_cvt_pk_f32_fp8(u.z, 0), exv, acc[4]);
    acc[5] = __builtin_elementwise_fma(__builtin_amdgcn_cvt_pk_f32_fp8(u.z, 1), exv, acc[5]);
    acc[6] = __builtin_elementwise_fma(__builtin_amdgcn_cvt_pk_f32_fp8(u.w, 0), exv, acc[6]);
    acc[7] = __builtin_elementwise_fma(__builtin_amdgcn_cvt_pk_f32_fp8(u.w, 1), exv, acc[7]);
}

// ---------------- P1: per-block bucket histogram + fused weight prep ----------------
__global__ __launch_bounds__(256) void p1_kernel(
        const int* __restrict__ dst, int* __restrict__ bhist,
        const float* __restrict__ W1, const float* __restrict__ W2,
        const float* __restrict__ al1, const float* __restrict__ ar1,
        unsigned short* __restrict__ W1E, unsigned short* __restrict__ W2T) {
    __shared__ float tile[64][65];
    __shared__ int hist[NBUCK];
    int b = blockIdx.x, t = threadIdx.x;
    if (b < NBLK) {
        if (t < NBUCK) hist[t] = 0;
        __syncthreads();
        int e = (b * 256 + t) * 4;
        if (e < N_EDGES) {
            int4 d = *(const int4*)&dst[e];
            atomicAdd(&hist[d.x >> 8], 1);
            atomicAdd(&hist[d.y >> 8], 1);
            atomicAdd(&hist[d.z >> 8], 1);
            atomicAdd(&hist[d.w >> 8], 1);
        }
        __syncthreads();
        if (t < NBUCK) bhist[t * NBLK + b] = hist[t];
        return;
    }
    int pb = b - NBLK;
    if (pb < 16) {
        int tk = (pb & 3) * 64, tn = (pb >> 2) * 64;
        int tx = t & 63, ty = t >> 6;
#pragma unroll
        for (int r = 0; r < 16; ++r) {
            int row = ty * 16 + r;
            tile[row][tx] = W1[(tk + row) * 256 + tn + tx];
        }
        __syncthreads();
#pragma unroll
        for (int r = 0; r < 16; ++r) {
            int row = ty * 16 + r;
            W1E[(tn + row) * 256 + tk + tx] = f2b(tile[tx][row]);
        }
    } else if (pb < 20) {
        int h = pb - 16;
        int w = t >> 6, lane = t & 63;
        float alv = al1[h * 64 + lane];
        float arv = ar1[h * 64 + lane];
        for (int k = w; k < 256; k += 4) {
            float wv = W1[k * 256 + h * 64 + lane];
            float sl = wv * alv, sr = wv * arv;
#pragma unroll
            for (int off = 1; off < 64; off <<= 1) {
                sl += __shfl_xor(sl, off);
                sr += __shfl_xor(sr, off);
            }
            if (lane == 0) {
                W1E[(256 + h) * 256 + k] = f2b(sl);
                W1E[(260 + h) * 256 + k] = f2b(sr);
            }
        }
    } else {
        int n = t >> 4, k0 = (t & 15) * 16;
#pragma unroll
        for (int j = 0; j < 16; ++j)
            W2T[n * 256 + k0 + j] = f2b(W2[(k0 + j) * 16 + n]);
#pragma unroll
        for (int j = 0; j < 8; ++j)
            W1E[264 * 256 + j * 256 + t] = 0;
    }
}

// ---------------- scanA: per-chunk (1024) exclusive scan of bhist ----------------
__global__ __launch_bounds__(256) void scanA_kernel(const int* __restrict__ bhist,
                                                    int* __restrict__ partial,
                                                    int* __restrict__ bsum) {
    __shared__ int wsum[4];
    int t = threadIdx.x;
    int base = blockIdx.x * 1024 + t * 4;
    int v0 = (base + 0 < NSCAN) ? bhist[base + 0] : 0;
    int v1 = (base + 1 < NSCAN) ? bhist[base + 1] : 0;
    int v2 = (base + 2 < NSCAN) ? bhist[base + 2] : 0;
    int v3 = (base + 3 < NSCAN) ? bhist[base + 3] : 0;
    int s = v0 + v1 + v2 + v3;
    int lane = t & 63, w = t >> 6;
    int incl = s;
#pragma unroll
    for (int off = 1; off < 64; off <<= 1) {
        int x = __shfl_up(incl, off);
        if (lane >= off) incl += x;
    }
    if (lane == 63) wsum[w] = incl;
    __syncthreads();
    int woff = 0;
    for (int k = 0; k < w; ++k) woff += wsum[k];
    int excl = woff + incl - s;
    if (base + 0 < NSCAN) partial[base + 0] = excl;
    if (base + 1 < NSCAN) partial[base + 1] = excl + v0;
    if (base + 2 < NSCAN) partial[base + 2] = excl + v0 + v1;
    if (base + 3 < NSCAN) partial[base + 3] = excl + v0 + v1 + v2;
    if (t == 255) bsum[blockIdx.x] = woff + incl;
}

// ---------------- P2+GEMM1 merged dispatch ----------------
// blocks [0, NGB): gemm1 (MFMA-heavy);  blocks [NGB, NGB+NBLK): p2 edge presort
__global__ __launch_bounds__(256, 2) void p2g1_kernel(
        const int* __restrict__ src, const int* __restrict__ dst,
        const int* __restrict__ partial, const int* __restrict__ bsum,
        unsigned int* __restrict__ ebuf,
        const float* __restrict__ X, const unsigned short* __restrict__ BT,
        unsigned char* __restrict__ C, float* __restrict__ el, float* __restrict__ er) {
    // gemm1 LDS
    __shared__ __align__(16) unsigned short As[128 * 40];
    __shared__ __align__(16) unsigned short Bs[272 * 40];
    // p2 LDS
    __shared__ int wsum[4];
    __shared__ int sb[256];
    __shared__ int bs[NBUCK];
    __shared__ int lcnt[256];
    __shared__ int lofs[256];
    __shared__ int lfill[256];
    __shared__ unsigned int sorted[1024];

    int t = threadIdx.x;
    if (blockIdx.x >= NGB) {
        // ---- p2: LDS bucket presort ----
        int b = blockIdx.x - NGB;
        int lane = t & 63, w = t >> 6;
        {
            int v = (t < NSCB) ? bsum[t] : 0;
            int incl = v;
#pragma unroll
            for (int off = 1; off < 64; off <<= 1) {
                int x = __shfl_up(incl, off);
                if (lane >= off) incl += x;
            }
            if (lane == 63) wsum[w] = incl;
            __syncthreads();
            int woff = 0;
            for (int k = 0; k < w; ++k) woff += wsum[k];
            sb[t] = woff + incl - v;
        }
        lcnt[t] = 0;
        __syncthreads();
        if (t < NBUCK) {
            int idx = t * NBLK + b;
            bs[t] = partial[idx] + sb[idx >> 10];
        }
        int e = (b * 256 + t) * 4;
        int4 d, s;
        bool valid = e < N_EDGES;
        if (valid) {
            d = *(const int4*)&dst[e];
            s = *(const int4*)&src[e];
            atomicAdd(&lcnt[d.x >> 8], 1);
            atomicAdd(&lcnt[d.y >> 8], 1);
            atomicAdd(&lcnt[d.z >> 8], 1);
            atomicAdd(&lcnt[d.w >> 8], 1);
        }
        __syncthreads();
        {
            int v = lcnt[t];
            int incl = v;
#pragma unroll
            for (int off = 1; off < 64; off <<= 1) {
                int x = __shfl_up(incl, off);
                if (lane >= off) incl += x;
            }
            if (lane == 63) wsum[w] = incl;
            __syncthreads();
            int woff = 0;
            for (int k = 0; k < w; ++k) woff += wsum[k];
            int excl = woff + incl - v;
            lofs[t] = excl;
            lfill[t] = excl;
        }
        __syncthreads();
        if (valid) {
            int p0 = atomicAdd(&lfill[d.x >> 8], 1);
            sorted[p0] = ((unsigned int)s.x << 16) | (unsigned int)d.x;
            int p1 = atomicAdd(&lfill[d.y >> 8], 1);
            sorted[p1] = ((unsigned int)s.y << 16) | (unsigned int)d.y;
            int p2 = atomicAdd(&lfill[d.z >> 8], 1);
            sorted[p2] = ((unsigned int)s.z << 16) | (unsigned int)d.z;
            int p3 = atomicAdd(&lfill[d.w >> 8], 1);
            sorted[p3] = ((unsigned int)s.w << 16) | (unsigned int)d.w;
        }
        __syncthreads();
        int ve = min(1024, N_EDGES - b * 1024);
        for (int i = t; i < ve; i += 256) {
            unsigned int p = sorted[i];
            int k = (p & 0xFFFFu) >> 8;
            ebuf[bs[k] + (i - lofs[k])] = p;
        }
        return;
    }

    // ---- gemm1: [feat1(fp8) | el | er] = x @ [W1 | Wel | Wer] ----
    int m0 = blockIdx.x * 128;
    int lane = t & 63, wm = t >> 6;
    int quad = lane >> 4, l16 = lane & 15;

    floatx4 acc[2][17];
#pragma unroll
    for (int i = 0; i < 2; ++i)
#pragma unroll
        for (int j = 0; j < 17; ++j) acc[i][j] = (floatx4){0.f, 0.f, 0.f, 0.f};

    int arow = t >> 1, ak = (t & 1) * 16;
    int grow = m0 + arow;
    const float* xrow = X + (size_t)grow * 256 + ak;

    for (int k0 = 0; k0 < 256; k0 += 32) {
        float4 v0 = make_float4(0.f, 0.f, 0.f, 0.f), v1 = v0, v2 = v0, v3 = v0;
        if (grow < N_NODES) {
            v0 = *(const float4*)(xrow + k0 + 0);
            v1 = *(const float4*)(xrow + k0 + 4);
            v2 = *(const float4*)(xrow + k0 + 8);
            v3 = *(const float4*)(xrow + k0 + 12);
        }
        uint4 p0, p1;
        p0.x = pack2(v0.x, v0.y); p0.y = pack2(v0.z, v0.w);
        p0.z = pack2(v1.x, v1.y); p0.w = pack2(v1.z, v1.w);
        p1.x = pack2(v2.x, v2.y); p1.y = pack2(v2.z, v2.w);
        p1.z = pack2(v3.x, v3.y); p1.w = pack2(v3.z, v3.w);
        *(uint4*)&As[arow * 40 + ak] = p0;
        *(uint4*)&As[arow * 40 + ak + 8] = p1;
#pragma unroll
        for (int i = 0; i < 5; ++i) {
            int ch = t + i * 256;
            if (ch < 1088) {
                int row = ch >> 2, off = (ch & 3) * 8;
                *(uint4*)&Bs[row * 40 + off] = *(const uint4*)(BT + row * 256 + k0 + off);
            }
        }
        __syncthreads();

        short8 a0 = *(const short8*)&As[(wm * 32 + l16) * 40 + quad * 8];
        short8 a1 = *(const short8*)&As[(wm * 32 + 16 + l16) * 40 + quad * 8];
#pragma unroll
        for (int nf = 0; nf < 17; ++nf) {
            short8 bb = *(const short8*)&Bs[(nf * 16 + l16) * 40 + quad * 8];
            acc[0][nf] = __builtin_amdgcn_mfma_f32_16x16x32_bf16(a0, bb, acc[0][nf], 0, 0, 0);
            acc[1][nf] = __builtin_amdgcn_mfma_f32_16x16x32_bf16(a1, bb, acc[1][nf], 0, 0, 0);
        }
        __syncthreads();
    }

#pragma unroll
    for (int mf = 0; mf < 2; ++mf) {
#pragma unroll
        for (int r = 0; r < 4; ++r) {
            int row = m0 + wm * 32 + mf * 16 + quad * 4 + r;
            if (row < N_NODES && l16 < 8) {
                float v = acc[mf][16][r];
                if (l16 < 4) el[row * 4 + l16] = v;
                else er[row * 4 + (l16 - 4)] = v;
            }
        }
    }

    unsigned short* scr = Bs + wm * 1536;
    int half = lane >> 5, l32 = lane & 31;
    int rrow = l32 >> 1, coff = (l32 & 1) * 8;
#pragma unroll
    for (int mf = 0; mf < 2; ++mf) {
#pragma unroll
        for (int p = 0; p < 8; ++p) {
            unsigned short* base = scr + (p & 1) * 768;
#pragma unroll
            for (int fr = 0; fr < 2; ++fr) {
                int nf = 2 * p + fr;
                unsigned short* fb = base + fr * 384;
#pragma unroll
                for (int r = 0; r < 4; ++r)
                    fb[(quad * 4 + r) * 24 + l16] = f2b(acc[mf][nf][r]);
            }
            uint4 val = *(const uint4*)(base + half * 384 + rrow * 24 + coff);
            int row = m0 + wm * 32 + mf * 16 + rrow;
            int nf = 2 * p + half;
            if (row < N_NODES) {
                float f0 = blo(val.x), f1 = bhi(val.x), f2 = blo(val.y), f3 = bhi(val.y);
                float f4 = blo(val.z), f5 = bhi(val.z), f6 = blo(val.w), f7 = bhi(val.w);
                int lo = __builtin_amdgcn_cvt_pk_fp8_f32(f0, f1, 0, 0);
                lo = __builtin_amdgcn_cvt_pk_fp8_f32(f2, f3, lo, 1);
                int hi = __builtin_amdgcn_cvt_pk_fp8_f32(f4, f5, 0, 0);
                hi = __builtin_amdgcn_cvt_pk_fp8_f32(f6, f7, hi, 1);
                uint2 o;
                o.x = (unsigned int)lo;
                o.y = (unsigned int)hi;
                *(uint2*)&C[(size_t)row * 256 + nf * 16 + coff] = o;
            }
        }
    }
}

// ---------------- P3: per-bucket LDS node presort -> coalesced csr_src + row_ptr ----------------
__global__ __launch_bounds__(256) void p3_kernel(const int* __restrict__ partial,
                                                 const int* __restrict__ bsum,
                                                 const unsigned int* __restrict__ ebuf,
                                                 int* __restrict__ row_ptr,
                                                 int* __restrict__ csr_src) {
    __shared__ int wsum[4];
    __shared__ int sb[256];
    __shared__ int lcnt[256];
    __shared__ int lfill[256];
    __shared__ int sorted[MAXB];
    int b = blockIdx.x, t = threadIdx.x;
    int lane = t & 63, w = t >> 6;
    {
        int v = (t < NSCB) ? bsum[t] : 0;
        int incl = v;
#pragma unroll
        for (int off = 1; off < 64; off <<= 1) {
            int x = __shfl_up(incl, off);
            if (lane >= off) incl += x;
        }
        if (lane == 63) wsum[w] = incl;
        __syncthreads();
        int woff = 0;
        for (int k = 0; k < w; ++k) woff += wsum[k];
        sb[t] = woff + incl - v;
    }
    __syncthreads();
    int i0 = b * NBLK;
    int base = partial[i0] + sb[i0 >> 10];
    int endb;
    if (b == NBUCK - 1) endb = N_EDGES;
    else {
        int i1 = (b + 1) * NBLK;
        endb = partial[i1] + sb[i1 >> 10];
    }
    lcnt[t] = 0;
    __syncthreads();
    for (int i = base + t; i < endb; i += 256)
        atomicAdd(&lcnt[ebuf[i] & 255u], 1);
    __syncthreads();
    {
        int v = lcnt[t];
        int incl = v;
#pragma unroll
        for (int off = 1; off < 64; off <<= 1) {
            int x = __shfl_up(incl, off);
            if (lane >= off) incl += x;
        }
        if (lane == 63) wsum[w] = incl;
        __syncthreads();
        int woff = 0;
        for (int k = 0; k < w; ++k) woff += wsum[k];
        int excl = woff + incl - v;
        lfill[t] = excl;
        int node = b * 256 + t;
        if (node < NP1) row_ptr[node] = base + excl;
    }
    __syncthreads();
    for (int i = base + t; i < endb; i += 256) {
        unsigned int p = ebuf[i];
        int pos = atomicAdd(&lfill[p & 255u], 1);
        sorted[pos] = (int)(p >> 16);
    }
    __syncthreads();
    int M = endb - base;
    for (int i = t; i < M; i += 256)
        csr_src[base + i] = sorted[i];
}

// ---------------- layer-1 aggregation: fp8 gather + packed fp32 accumulate ----------------
__global__ void agg1_kernel(const unsigned char* __restrict__ feat1,
                            const float* __restrict__ el, const float* __restrict__ er,
                            const int* __restrict__ row_ptr, const int* __restrict__ csr_src,
                            const float* __restrict__ b1, unsigned short* __restrict__ h1b) {
    int wave = threadIdx.x >> 6, lane = threadIdx.x & 63;
    int n = blockIdx.x * 4 + wave;
    if (n >= N_NODES) return;
    int q = lane >> 4, l16 = lane & 15;
    int h = l16 >> 2;
    float er_h = er[n * 4 + h];
    int start = row_ptr[n], end = row_ptr[n + 1];

    floatx2 acc2[8];
#pragma unroll
    for (int j = 0; j < 8; ++j) acc2[j] = (floatx2){0.f, 0.f};
    float denom = 0.f;

    int i = start + q;
    for (; i + 4 < end; i += 8) {
        int s0 = csr_src[i];
        int s1 = csr_src[i + 4];
        float ex0 = __expf(leaky(el[s0 * 4 + h] + er_h));
        float ex1 = __expf(leaky(el[s1 * 4 + h] + er_h));
        uint4 a = *(const uint4*)(feat1 + (size_t)s0 * 256 + l16 * 16);
        uint4 b = *(const uint4*)(feat1 + (size_t)s1 * 256 + l16 * 16);
        denom += ex0 + ex1;
        fp8acc2(a, (floatx2){ex0, ex0}, acc2);
        fp8acc2(b, (floatx2){ex1, ex1}, acc2);
    }
    if (i < end) {
        int s = csr_src[i];
        float ex = __expf(leaky(el[s * 4 + h] + er_h));
        uint4 u = *(const uint4*)(feat1 + (size_t)s * 256 + l16 * 16);
        denom += ex;
        fp8acc2(u, (floatx2){ex, ex}, acc2);
    }
    float acc[16];
#pragma unroll
    for (int j = 0; j < 8; ++j) {
        acc[2 * j] = acc2[j][0];
        acc[2 * j + 1] = acc2[j][1];
    }
#pragma unroll
    for (int j = 0; j < 16; ++j) {
        acc[j] += __shfl_xor(acc[j], 16);
        acc[j] += __shfl_xor(acc[j], 32);
    }
    denom += __shfl_xor(denom, 16);
    denom += __shfl_xor(denom, 32);

    if (q == 0) {
        float inv = (end > start) ? 1.f / denom : 0.f;
        float o[16];
#pragma unroll
        for (int j = 0; j < 16; j += 4) {
            float4 b4 = *(const float4*)&b1[l16 * 16 + j];
            o[j + 0] = fmaf(acc[j + 0], inv, b4.x);
            o[j + 1] = fmaf(acc[j + 1], inv, b4.y);
            o[j + 2] = fmaf(acc[j + 2], inv, b4.z);
            o[j + 3] = fmaf(acc[j + 3], inv, b4.w);
        }
#pragma unroll
        for (int j = 0; j < 16; ++j) o[j] = o[j] > 0.f ? o[j] : __expf(o[j]) - 1.f;
        uint4 pa, pb;
        pa.x = pack2(o[0], o[1]);   pa.y = pack2(o[2], o[3]);
        pa.z = pack2(o[4], o[5]);   pa.w = pack2(o[6], o[7]);
        pb.x = pack2(o[8], o[9]);   pb.y = pack2(o[10], o[11]);
        pb.z = pack2(o[12], o[13]); pb.w = pack2(o[14], o[15]);
        uint4* dstp = (uint4*)(h1b + (size_t)n * 256 + l16 * 16);
        dstp[0] = pa;
        dstp[1] = pb;
    }
}

// ---------------- GEMM2 (bf16 MFMA, no LDS) + fused el2/er2, bf16 feat2 out ----------------
__global__ __launch_bounds__(256) void gemm2_mfma_kernel(
        const unsigned short* __restrict__ h1b, const unsigned short* __restrict__ W2T,
        const float* __restrict__ al2, const float* __restrict__ ar2,
        unsigned short* __restrict__ feat2b, float* __restrict__ el2, float* __restrict__ er2) {
    int wave = threadIdx.x >> 6, lane = threadIdx.x & 63;
    int l16 = lane & 15, quad = lane >> 4;
    int row0 = (blockIdx.x * 4 + wave) * 16;
    if (row0 >= N_NODES) return;
    floatx4 acc = (floatx4){0.f, 0.f, 0.f, 0.f};
    const unsigned short* arow = h1b + (size_t)(row0 + l16) * 256 + quad * 8;
    const unsigned short* brow = W2T + (size_t)l16 * 256 + quad * 8;
#pragma unroll
    for (int k0 = 0; k0 < 256; k0 += 32) {
        short8 a = *(const short8*)(arow + k0);
        short8 b = *(const short8*)(brow + k0);
        acc = __builtin_amdgcn_mfma_f32_16x16x32_bf16(a, b, acc, 0, 0, 0);
    }
    float a2 = al2[l16], r2 = ar2[l16];
#pragma unroll
    for (int r = 0; r < 4; ++r) {
        int row = row0 + quad * 4 + r;
        float v = acc[r];
        feat2b[row * 16 + l16] = f2b(v);
        float pl = v * a2, pr = v * r2;
#pragma unroll
        for (int off = 1; off < 16; off <<= 1) {
            pl += __shfl_xor(pl, off);
            pr += __shfl_xor(pr, off);
        }
        if (l16 == 0) {
            el2[row] = pl;
            er2[row] = pr;
        }
    }
}

// ---------------- layer-2 aggregation + log_softmax, bf16 feat2, 2x unroll ----------------
__global__ void agg2_kernel(const unsigned short* __restrict__ feat2b,
                            const float* __restrict__ el2, const float* __restrict__ er2,
                            const int* __restrict__ row_ptr, const int* __restrict__ csr_src,
                            const float* __restrict__ b2, float* __restrict__ out) {
    int wave = threadIdx.x >> 6, lane = threadIdx.x & 63;
    int n = blockIdx.x * 4 + wave;
    if (n >= N_NODES) return;
    int start = row_ptr[n], end = row_ptr[n + 1];
    float ern = er2[n];
    int eo = lane >> 4, c = lane & 15;
    float acc = 0.f, denom = 0.f;
    int i = start + eo;
    for (; i + 4 < end; i += 8) {
        int s0 = csr_src[i], s1 = csr_src[i + 4];
        float ex0 = __expf(leaky(el2[s0] + ern));
        float ex1 = __expf(leaky(el2[s1] + ern));
        float f0 = b2f(feat2b[s0 * 16 + c]), f1 = b2f(feat2b[s1 * 16 + c]);
        denom += ex0 + ex1;
        acc = fmaf(f0, ex0, acc);
        acc = fmaf(f1, ex1, acc);
    }
    if (i < end) {
        int s = csr_src[i];
        float ex = __expf(leaky(el2[s] + ern));
        denom += ex;
        acc = fmaf(b2f(feat2b[s * 16 + c]), ex, acc);
    }
    acc += __shfl_xor(acc, 16);
    acc += __shfl_xor(acc, 32);
    denom += __shfl_xor(denom, 16);
    denom += __shfl_xor(denom, 32);
    float v = ((end > start) ? acc / denom : 0.f) + b2[c];
    float mx = v;
#pragma unroll
    for (int off = 1; off < 16; off <<= 1) mx = fmaxf(mx, __shfl_xor(mx, off));
    float ex2 = __expf(v - mx);
    float s2 = ex2;
#pragma unroll
    for (int off = 1; off < 16; off <<= 1) s2 += __shfl_xor(s2, off);
    float res = v - mx - logf(s2);
    if (lane < 16) out[n * 16 + lane] = res;
}

// ---------------- launch ----------------
extern "C" void kernel_launch(void* const* d_in, const int* in_sizes, int n_in,
                              void* d_out, int out_size, void* d_ws, size_t ws_size,
                              hipStream_t stream) {
    const float* x   = (const float*)d_in[0];
    const int*   src = (const int*)d_in[1];
    const int*   dst = (const int*)d_in[2];
    const float* W1  = (const float*)d_in[3];
    const float* al1 = (const float*)d_in[4];
    const float* ar1 = (const float*)d_in[5];
    const float* b1  = (const float*)d_in[6];
    const float* W2  = (const float*)d_in[7];
    const float* al2 = (const float*)d_in[8];
    const float* ar2 = (const float*)d_in[9];
    const float* b2  = (const float*)d_in[10];
    float* out = (float*)d_out;

    char* ws = (char*)d_ws;
    size_t off = 0;
    auto alloc = [&](size_t bytes) -> void* {
        void* p = ws + off;
        off += (bytes + 255) & ~(size_t)255;
        return p;
    };
    unsigned short* W1E    = (unsigned short*)alloc((size_t)272 * 256 * 2);
    unsigned short* W2T    = (unsigned short*)alloc((size_t)16 * 256 * 2);
    unsigned char*  feat1  = (unsigned char*)alloc((size_t)N_NODES * 256);
    unsigned short* h1b    = (unsigned short*)alloc((size_t)N_NODES * 256 * 2);
    unsigned short* feat2b = (unsigned short*)alloc((size_t)N_NODES * 16 * 2);
    float* el1     = (float*)alloc((size_t)N_NODES * 4 * 4);
    float* er1     = (float*)alloc((size_t)N_NODES * 4 * 4);
    float* el2     = (float*)alloc((size_t)N_NODES * 4);
    float* er2     = (float*)alloc((size_t)N_NODES * 4);
    int*   bhist   = (int*)alloc((size_t)NSCAN * 4);
    int*   partial = (int*)alloc((size_t)NSCAN * 4);
    int*   bsum    = (int*)alloc((size_t)256 * 4);
    int*   row_ptr = (int*)alloc((size_t)NP1 * 4);
    unsigned int* ebuf = (unsigned int*)alloc((size_t)N_EDGES * 4);
    int*   csr_src = (int*)alloc((size_t)N_EDGES * 4);

    dim3 b256(256);
    p1_kernel<<<NBLK + 21, b256, 0, stream>>>(dst, bhist, W1, W2, al1, ar1, W1E, W2T);
    scanA_kernel<<<NSCB, b256, 0, stream>>>(bhist, partial, bsum);
    p2g1_kernel<<<NGB + NBLK, b256, 0, stream>>>(src, dst, partial, bsum, ebuf,
                                                 x, W1E, feat1, el1, er1);
    p3_kernel<<<NBUCK, b256, 0, stream>>>(partial, bsum, ebuf, row_ptr, csr_src);

    agg1_kernel<<<(N_NODES + 3) / 4, b256, 0, stream>>>(feat1, el1, er1, row_ptr, csr_src, b1, h1b);

    gemm2_mfma_kernel<<<(N_NODES + 63) / 64, b256, 0, stream>>>(h1b, W2T, al2, ar2, feat2b, el2, er2);
    agg2_kernel<<<(N_NODES + 3) / 4, b256, 0, stream>>>(feat2b, el2, er2, row_ptr, csr_src, b2, out);
}